// Round 1
// baseline (1076.725 us; speedup 1.0000x reference)
//
#include <hip/hip_runtime.h>
#include <hip/hip_bf16.h>

typedef __attribute__((ext_vector_type(8))) short short8;
typedef __attribute__((ext_vector_type(4))) float f32x4;

__device__ __forceinline__ ushort f2bf(float f) {
    unsigned u = __float_as_uint(f);
    u += 0x7FFFu + ((u >> 16) & 1u);
    return (ushort)(u >> 16);
}
__device__ __forceinline__ float bf2f(ushort h) {
    return __uint_as_float(((unsigned)h) << 16);
}

// ---------------- CSR build ----------------
__global__ void k_deg_init(int* deg, int n) {
    int i = blockIdx.x * blockDim.x + threadIdx.x;
    if (i < n) deg[i] = 1;  // self loop
}
__global__ void k_hist(const int* __restrict__ dst, int* __restrict__ deg, int e) {
    int i = blockIdx.x * blockDim.x + threadIdx.x;
    if (i < e) atomicAdd(&deg[dst[i]], 1);
}
__global__ void k_scanA(const int* __restrict__ deg, int* __restrict__ bsum, int n) {
    __shared__ int sd[256];
    int t = blockIdx.x * 256 + threadIdx.x;
    sd[threadIdx.x] = (t < n) ? deg[t] : 0;
    __syncthreads();
    for (int off = 128; off > 0; off >>= 1) {
        if (threadIdx.x < off) sd[threadIdx.x] += sd[threadIdx.x + off];
        __syncthreads();
    }
    if (threadIdx.x == 0) bsum[blockIdx.x] = sd[0];
}
__global__ void k_scanB(const int* __restrict__ bsum, int* __restrict__ boff, int nb) {
    __shared__ int sd[256];
    int i = threadIdx.x;
    int v = (i < nb) ? bsum[i] : 0;
    sd[i] = v;
    __syncthreads();
    for (int off = 1; off < 256; off <<= 1) {
        int t = (i >= off) ? sd[i - off] : 0;
        __syncthreads();
        sd[i] += t;
        __syncthreads();
    }
    if (i < nb) boff[i] = sd[i] - v;  // exclusive
}
__global__ void k_scanC(const int* __restrict__ deg, const int* __restrict__ boff,
                        int* __restrict__ rowptr, int* __restrict__ cursor, int n, int etot) {
    __shared__ int sd[256];
    int t = blockIdx.x * 256 + threadIdx.x;
    int i = threadIdx.x;
    int v = (t < n) ? deg[t] : 0;
    sd[i] = v;
    __syncthreads();
    for (int off = 1; off < 256; off <<= 1) {
        int tv = (i >= off) ? sd[i - off] : 0;
        __syncthreads();
        sd[i] += tv;
        __syncthreads();
    }
    if (t < n) {
        int ex = boff[blockIdx.x] + sd[i] - v;
        rowptr[t] = ex;
        cursor[t] = ex;
        if (t == n - 1) rowptr[n] = etot;
    }
}
__global__ void k_scatter(const int* __restrict__ ei, int* __restrict__ cursor,
                          int* __restrict__ col, int e, int n) {
    int i = blockIdx.x * blockDim.x + threadIdx.x;
    int etot = e + n;
    if (i >= etot) return;
    int s, d;
    if (i < e) { s = ei[i]; d = ei[e + i]; }
    else       { s = i - e; d = s; }
    int pos = atomicAdd(&cursor[d], 1);
    col[pos] = s;
}

// ---------------- weight transpose + bf16 cvt ----------------
__global__ void k_wcvt(const float* __restrict__ W, ushort* __restrict__ WT, int K, int Nc) {
    int i = blockIdx.x * blockDim.x + threadIdx.x;
    if (i < K * Nc) {
        int k = i / Nc, c = i % Nc;
        WT[(size_t)c * K + k] = f2bf(W[i]);
    }
}

// ---------------- GEMM: C[M,Nc] = A[M,K] x B[K,Nc], B given as BT[Nc][K] bf16 ----------------
// block = 256 thr = 4 waves; wave w computes rows [blk*64+16w, +16), all Nc=NT*16 cols.
template <int K, int NT, bool AF32, bool STORE_BF>
__global__ __launch_bounds__(256) void k_gemm(const void* __restrict__ Ap,
                                              const ushort* __restrict__ BT,
                                              void* __restrict__ Cp, int M) {
    const int Nc = NT * 16;
    int wave = threadIdx.x >> 6;
    int lane = threadIdx.x & 63;
    int lr = lane & 15, lg = lane >> 4;
    int r0 = blockIdx.x * 64 + wave * 16;

    f32x4 acc[NT];
#pragma unroll
    for (int t = 0; t < NT; ++t) acc[t] = f32x4{0.f, 0.f, 0.f, 0.f};

    int arow = r0 + lr;
    if (arow >= M) arow = M - 1;

    for (int kk = 0; kk < K; kk += 32) {
        int ka = kk + lg * 8;
        short8 a;
        if (AF32) {
            const float* A = (const float*)Ap;
            const float* p = A + (size_t)arow * K + ka;
            f32x4 lo = *(const f32x4*)p;
            f32x4 hi = *(const f32x4*)(p + 4);
            a[0] = (short)f2bf(lo[0]); a[1] = (short)f2bf(lo[1]);
            a[2] = (short)f2bf(lo[2]); a[3] = (short)f2bf(lo[3]);
            a[4] = (short)f2bf(hi[0]); a[5] = (short)f2bf(hi[1]);
            a[6] = (short)f2bf(hi[2]); a[7] = (short)f2bf(hi[3]);
        } else {
            const ushort* A = (const ushort*)Ap;
            a = *(const short8*)(A + (size_t)arow * K + ka);
        }
#pragma unroll
        for (int t = 0; t < NT; ++t) {
            short8 b = *(const short8*)(BT + (size_t)(t * 16 + lr) * K + ka);
            acc[t] = __builtin_amdgcn_mfma_f32_16x16x32_bf16(a, b, acc[t], 0, 0, 0);
        }
    }
#pragma unroll
    for (int t = 0; t < NT; ++t) {
        int colc = t * 16 + lr;
#pragma unroll
        for (int p = 0; p < 4; ++p) {
            int row = r0 + lg * 4 + p;
            if (row < M) {
                if (STORE_BF)
                    ((ushort*)Cp)[(size_t)row * Nc + colc] = f2bf(acc[t][p]);
                else
                    ((float*)Cp)[(size_t)row * Nc + colc] = acc[t][p];
            }
        }
    }
}

// ---------------- attention coefficients ----------------
__global__ void k_alpha(const ushort* __restrict__ h, const float* __restrict__ a_src,
                        const float* __restrict__ a_dst, float* __restrict__ asrc,
                        float* __restrict__ adst, int n) {
    int i = blockIdx.x * blockDim.x + threadIdx.x;
    if (i >= n * 8) return;
    int node = i >> 3, hd = i & 7;
    const ushort* hp = h + (size_t)node * 256 + hd * 32;
    const float* as = a_src + hd * 32;
    const float* ad = a_dst + hd * 32;
    float s1 = 0.f, s2 = 0.f;
#pragma unroll
    for (int j = 0; j < 32; ++j) {
        float v = bf2f(hp[j]);
        s1 += v * as[j];
        s2 += v * ad[j];
    }
    asrc[i] = s1;
    adst[i] = s2;
}
__global__ void k_alpha2(const float* __restrict__ h2, const float* __restrict__ a_src,
                         const float* __restrict__ a_dst, float* __restrict__ asrc,
                         float* __restrict__ adst, int n) {
    int i = blockIdx.x * blockDim.x + threadIdx.x;
    if (i >= n) return;
    const float* hp = h2 + (size_t)i * 64;
    float s1 = 0.f, s2 = 0.f;
#pragma unroll
    for (int j = 0; j < 64; ++j) {
        float v = hp[j];
        s1 += v * a_src[j];
        s2 += v * a_dst[j];
    }
    asrc[i] = s1;
    adst[i] = s2;
}

// ---------------- aggregation, layers 0/1: out = bf16(ELU(agg + b)) ----------------
__global__ __launch_bounds__(256) void k_agg(const ushort* __restrict__ h,
                                             const float* __restrict__ asrc,
                                             const float* __restrict__ adst,
                                             const int* __restrict__ rowptr,
                                             const int* __restrict__ col,
                                             const float* __restrict__ bias,
                                             ushort* __restrict__ anext, int n) {
    int node = blockIdx.x;
    int c = threadIdx.x;
    int hd = c >> 5;
    int beg = rowptr[node], end = rowptr[node + 1];
    float ad = adst[node * 8 + hd];
    float m = -1e30f;
    for (int j = beg; j < end; ++j) {
        int s = col[j];
        float e = asrc[s * 8 + hd] + ad;
        e = (e >= 0.f) ? e : 0.2f * e;
        m = fmaxf(m, e);
    }
    float ssum = 0.f, acc = 0.f;
    for (int j = beg; j < end; ++j) {
        int s = col[j];
        float e = asrc[s * 8 + hd] + ad;
        e = (e >= 0.f) ? e : 0.2f * e;
        float w = __expf(e - m);
        ssum += w;
        acc += w * bf2f(h[(size_t)s * 256 + c]);
    }
    float v = acc / (ssum + 1e-16f) + bias[c];
    v = (v > 0.f) ? v : expm1f(v);
    anext[(size_t)node * 256 + c] = f2bf(v);
}

// ---------------- aggregation layer 2 (H=1, C=64) + bias + log_softmax ----------------
__global__ __launch_bounds__(256) void k_agg2(const float* __restrict__ h2,
                                              const float* __restrict__ asrc,
                                              const float* __restrict__ adst,
                                              const int* __restrict__ rowptr,
                                              const int* __restrict__ col,
                                              const float* __restrict__ bias,
                                              float* __restrict__ out, int n) {
    int wid = threadIdx.x >> 6;
    int lane = threadIdx.x & 63;
    int node = blockIdx.x * 4 + wid;
    if (node >= n) return;
    int beg = rowptr[node], end = rowptr[node + 1];
    float ad = adst[node];
    float m = -1e30f;
    for (int j = beg; j < end; ++j) {
        int s = col[j];
        float e = asrc[s] + ad;
        e = (e >= 0.f) ? e : 0.2f * e;
        m = fmaxf(m, e);
    }
    float ssum = 0.f, acc = 0.f;
    for (int j = beg; j < end; ++j) {
        int s = col[j];
        float e = asrc[s] + ad;
        e = (e >= 0.f) ? e : 0.2f * e;
        float w = __expf(e - m);
        ssum += w;
        acc += w * h2[(size_t)s * 64 + lane];
    }
    float v = acc / (ssum + 1e-16f) + bias[lane];
    // log_softmax over the 64 lanes
    float mx = v;
#pragma unroll
    for (int off = 32; off > 0; off >>= 1) mx = fmaxf(mx, __shfl_xor(mx, off));
    float ex = __expf(v - mx);
    float se = ex;
#pragma unroll
    for (int off = 32; off > 0; off >>= 1) se += __shfl_xor(se, off);
    out[(size_t)node * 64 + lane] = v - mx - logf(se);
}

extern "C" void kernel_launch(void* const* d_in, const int* in_sizes, int n_in,
                              void* d_out, int out_size, void* d_ws, size_t ws_size,
                              hipStream_t stream) {
    const float* x   = (const float*)d_in[0];
    const int*   ei  = (const int*)d_in[1];
    const float* W0  = (const float*)d_in[2];
    const float* as0 = (const float*)d_in[3];
    const float* ad0 = (const float*)d_in[4];
    const float* b0  = (const float*)d_in[5];
    const float* W1  = (const float*)d_in[6];
    const float* as1 = (const float*)d_in[7];
    const float* ad1 = (const float*)d_in[8];
    const float* b1  = (const float*)d_in[9];
    const float* W2  = (const float*)d_in[10];
    const float* as2 = (const float*)d_in[11];
    const float* ad2 = (const float*)d_in[12];
    const float* b2  = (const float*)d_in[13];
    float* out = (float*)d_out;

    const int N = in_sizes[0] / 512;   // 50000
    const int E = in_sizes[1] / 2;     // 800000
    const int ETOT = E + N;

    char* ws = (char*)d_ws;
    size_t off = 0;
    auto alloc = [&](size_t bytes) -> void* {
        off = (off + 255) & ~(size_t)255;
        void* p = ws + off;
        off += bytes;
        return p;
    };
    int* rowptr = (int*)alloc((size_t)(N + 1) * 4);
    int* cursor = (int*)alloc((size_t)N * 4);
    int* deg    = (int*)alloc((size_t)N * 4);
    int* bsum   = (int*)alloc(1024);
    int* boff   = (int*)alloc(1024);
    int* colb   = (int*)alloc((size_t)ETOT * 4);
    ushort* WT0 = (ushort*)alloc((size_t)256 * 512 * 2);
    ushort* WT1 = (ushort*)alloc((size_t)256 * 256 * 2);
    ushort* WT2 = (ushort*)alloc((size_t)64 * 256 * 2);
    ushort* hbf = (ushort*)alloc((size_t)N * 256 * 2);
    ushort* abf = (ushort*)alloc((size_t)N * 256 * 2);
    float* h2   = (float*)alloc((size_t)N * 64 * 4);
    float* asrc = (float*)alloc((size_t)N * 8 * 4);
    float* adst = (float*)alloc((size_t)N * 8 * 4);
    float* asrc2 = (float*)alloc((size_t)N * 4);
    float* adst2 = (float*)alloc((size_t)N * 4);

    const int nblk = (N + 255) / 256;  // 196

    // CSR build
    k_deg_init<<<(N + 255) / 256, 256, 0, stream>>>(deg, N);
    k_hist<<<(E + 255) / 256, 256, 0, stream>>>(ei + E, deg, E);
    k_scanA<<<nblk, 256, 0, stream>>>(deg, bsum, N);
    k_scanB<<<1, 256, 0, stream>>>(bsum, boff, nblk);
    k_scanC<<<nblk, 256, 0, stream>>>(deg, boff, rowptr, cursor, N, ETOT);
    k_scatter<<<(ETOT + 255) / 256, 256, 0, stream>>>(ei, cursor, colb, E, N);

    // weights
    k_wcvt<<<(512 * 256 + 255) / 256, 256, 0, stream>>>(W0, WT0, 512, 256);
    k_wcvt<<<(256 * 256 + 255) / 256, 256, 0, stream>>>(W1, WT1, 256, 256);
    k_wcvt<<<(256 * 64 + 255) / 256, 256, 0, stream>>>(W2, WT2, 256, 64);

    const int gblk = (N + 63) / 64;  // 782

    // layer 0
    k_gemm<512, 16, true, true><<<gblk, 256, 0, stream>>>(x, WT0, hbf, N);
    k_alpha<<<(N * 8 + 255) / 256, 256, 0, stream>>>(hbf, as0, ad0, asrc, adst, N);
    k_agg<<<N, 256, 0, stream>>>(hbf, asrc, adst, rowptr, colb, b0, abf, N);

    // layer 1
    k_gemm<256, 16, false, true><<<gblk, 256, 0, stream>>>(abf, WT1, hbf, N);
    k_alpha<<<(N * 8 + 255) / 256, 256, 0, stream>>>(hbf, as1, ad1, asrc, adst, N);
    k_agg<<<N, 256, 0, stream>>>(hbf, asrc, adst, rowptr, colb, b1, abf, N);

    // layer 2
    k_gemm<256, 4, false, false><<<gblk, 256, 0, stream>>>(abf, WT2, h2, N);
    k_alpha2<<<(N + 255) / 256, 256, 0, stream>>>(h2, as2, ad2, asrc2, adst2, N);
    k_agg2<<<(N + 3) / 4, 256, 0, stream>>>(h2, asrc2, adst2, rowptr, colb, b2, out, N);
}

// Round 2
// 762.467 us; speedup vs baseline: 1.4122x; 1.4122x over previous
//
#include <hip/hip_runtime.h>
#include <hip/hip_bf16.h>

typedef __attribute__((ext_vector_type(8))) short short8;
typedef __attribute__((ext_vector_type(4))) float f32x4;
typedef __attribute__((ext_vector_type(4))) unsigned short us4;

__device__ __forceinline__ ushort f2bf(float f) {
    unsigned u = __float_as_uint(f);
    u += 0x7FFFu + ((u >> 16) & 1u);
    return (ushort)(u >> 16);
}
__device__ __forceinline__ float bf2f(ushort h) {
    return __uint_as_float(((unsigned)h) << 16);
}

// ---------------- CSR build ----------------
__global__ void k_deg_init(int* deg, int n) {
    int i = blockIdx.x * blockDim.x + threadIdx.x;
    if (i < n) deg[i] = 1;  // self loop
}
__global__ void k_hist(const int* __restrict__ dst, int* __restrict__ deg, int e) {
    int i = blockIdx.x * blockDim.x + threadIdx.x;
    if (i < e) atomicAdd(&deg[dst[i]], 1);
}
__global__ void k_scanA(const int* __restrict__ deg, int* __restrict__ bsum, int n) {
    __shared__ int sd[256];
    int t = blockIdx.x * 256 + threadIdx.x;
    sd[threadIdx.x] = (t < n) ? deg[t] : 0;
    __syncthreads();
    for (int off = 128; off > 0; off >>= 1) {
        if (threadIdx.x < off) sd[threadIdx.x] += sd[threadIdx.x + off];
        __syncthreads();
    }
    if (threadIdx.x == 0) bsum[blockIdx.x] = sd[0];
}
__global__ void k_scanB(const int* __restrict__ bsum, int* __restrict__ boff, int nb) {
    __shared__ int sd[256];
    int i = threadIdx.x;
    int v = (i < nb) ? bsum[i] : 0;
    sd[i] = v;
    __syncthreads();
    for (int off = 1; off < 256; off <<= 1) {
        int t = (i >= off) ? sd[i - off] : 0;
        __syncthreads();
        sd[i] += t;
        __syncthreads();
    }
    if (i < nb) boff[i] = sd[i] - v;  // exclusive
}
__global__ void k_scanC(const int* __restrict__ deg, const int* __restrict__ boff,
                        int* __restrict__ rowptr, int* __restrict__ cursor, int n, int etot) {
    __shared__ int sd[256];
    int t = blockIdx.x * 256 + threadIdx.x;
    int i = threadIdx.x;
    int v = (t < n) ? deg[t] : 0;
    sd[i] = v;
    __syncthreads();
    for (int off = 1; off < 256; off <<= 1) {
        int tv = (i >= off) ? sd[i - off] : 0;
        __syncthreads();
        sd[i] += tv;
        __syncthreads();
    }
    if (t < n) {
        int ex = boff[blockIdx.x] + sd[i] - v;
        rowptr[t] = ex;
        cursor[t] = ex;
        if (t == n - 1) rowptr[n] = etot;
    }
}
__global__ void k_scatter(const int* __restrict__ ei, int* __restrict__ cursor,
                          int* __restrict__ col, int e, int n) {
    int i = blockIdx.x * blockDim.x + threadIdx.x;
    int etot = e + n;
    if (i >= etot) return;
    int s, d;
    if (i < e) { s = ei[i]; d = ei[e + i]; }
    else       { s = i - e; d = s; }
    int pos = atomicAdd(&cursor[d], 1);
    col[pos] = s;
}

// ---------------- weight transpose + bf16 cvt ----------------
__global__ void k_wcvt(const float* __restrict__ W, ushort* __restrict__ WT, int K, int Nc) {
    int i = blockIdx.x * blockDim.x + threadIdx.x;
    if (i < K * Nc) {
        int k = i / Nc, c = i % Nc;
        WT[(size_t)c * K + k] = f2bf(W[i]);
    }
}

// ---------------- GEMM: C[M,Nc] = A[M,K] x B[K,Nc], B given as BT[Nc][K] bf16 ----------------
template <int K, int NT, bool AF32, bool STORE_BF>
__global__ __launch_bounds__(256) void k_gemm(const void* __restrict__ Ap,
                                              const ushort* __restrict__ BT,
                                              void* __restrict__ Cp, int M) {
    const int Nc = NT * 16;
    int wave = threadIdx.x >> 6;
    int lane = threadIdx.x & 63;
    int lr = lane & 15, lg = lane >> 4;
    int r0 = blockIdx.x * 64 + wave * 16;

    f32x4 acc[NT];
#pragma unroll
    for (int t = 0; t < NT; ++t) acc[t] = f32x4{0.f, 0.f, 0.f, 0.f};

    int arow = r0 + lr;
    if (arow >= M) arow = M - 1;

    for (int kk = 0; kk < K; kk += 32) {
        int ka = kk + lg * 8;
        short8 a;
        if (AF32) {
            const float* A = (const float*)Ap;
            const float* p = A + (size_t)arow * K + ka;
            f32x4 lo = *(const f32x4*)p;
            f32x4 hi = *(const f32x4*)(p + 4);
            a[0] = (short)f2bf(lo[0]); a[1] = (short)f2bf(lo[1]);
            a[2] = (short)f2bf(lo[2]); a[3] = (short)f2bf(lo[3]);
            a[4] = (short)f2bf(hi[0]); a[5] = (short)f2bf(hi[1]);
            a[6] = (short)f2bf(hi[2]); a[7] = (short)f2bf(hi[3]);
        } else {
            const ushort* A = (const ushort*)Ap;
            a = *(const short8*)(A + (size_t)arow * K + ka);
        }
#pragma unroll
        for (int t = 0; t < NT; ++t) {
            short8 b = *(const short8*)(BT + (size_t)(t * 16 + lr) * K + ka);
            acc[t] = __builtin_amdgcn_mfma_f32_16x16x32_bf16(a, b, acc[t], 0, 0, 0);
        }
    }
#pragma unroll
    for (int t = 0; t < NT; ++t) {
        int colc = t * 16 + lr;
#pragma unroll
        for (int p = 0; p < 4; ++p) {
            int row = r0 + lg * 4 + p;
            if (row < M) {
                if (STORE_BF)
                    ((ushort*)Cp)[(size_t)row * Nc + colc] = f2bf(acc[t][p]);
                else
                    ((float*)Cp)[(size_t)row * Nc + colc] = acc[t][p];
            }
        }
    }
}

// ---------------- attention coefficients (vectorized) ----------------
__global__ void k_alpha(const ushort* __restrict__ h, const float* __restrict__ a_src,
                        const float* __restrict__ a_dst, float* __restrict__ asrc,
                        float* __restrict__ adst, int n) {
    int i = blockIdx.x * blockDim.x + threadIdx.x;
    if (i >= n * 8) return;
    int node = i >> 3, hd = i & 7;
    const ushort* hp = h + (size_t)node * 256 + hd * 32;
    const float* as = a_src + hd * 32;
    const float* ad = a_dst + hd * 32;
    float s1 = 0.f, s2 = 0.f;
#pragma unroll
    for (int c = 0; c < 4; ++c) {
        short8 hv = *(const short8*)(hp + c * 8);
#pragma unroll
        for (int j = 0; j < 8; ++j) {
            float v = bf2f((ushort)hv[j]);
            s1 += v * as[c * 8 + j];
            s2 += v * ad[c * 8 + j];
        }
    }
    asrc[i] = s1;
    adst[i] = s2;
}
__global__ void k_alpha2(const float* __restrict__ h2, const float* __restrict__ a_src,
                         const float* __restrict__ a_dst, float* __restrict__ asrc,
                         float* __restrict__ adst, int n) {
    int i = blockIdx.x * blockDim.x + threadIdx.x;
    if (i >= n) return;
    const float* hp = h2 + (size_t)i * 64;
    float s1 = 0.f, s2 = 0.f;
#pragma unroll
    for (int j = 0; j < 64; ++j) {
        float v = hp[j];
        s1 += v * a_src[j];
        s2 += v * a_dst[j];
    }
    asrc[i] = s1;
    adst[i] = s2;
}

// ---------------- softmax weights: one thread per (node, head) ----------------
// wei[j*8+h] gets UNNORMALIZED exp(e - m); invs[node*8+h] = 1/sum.
__global__ void k_wei(const float* __restrict__ asrc, const float* __restrict__ adst,
                      const int* __restrict__ rowptr, const int* __restrict__ col,
                      float* __restrict__ wei, float* __restrict__ invs, int n) {
    int i = blockIdx.x * blockDim.x + threadIdx.x;
    if (i >= n * 8) return;
    int node = i >> 3, hd = i & 7;
    int beg = rowptr[node], end = rowptr[node + 1];
    float ad = adst[i];
    float m = -1e30f;
    for (int j = beg; j < end; ++j) {
        int s = col[j];
        float e = asrc[s * 8 + hd] + ad;
        e = (e >= 0.f) ? e : 0.2f * e;
        wei[(size_t)j * 8 + hd] = e;
        m = fmaxf(m, e);
    }
    float ssum = 0.f;
    for (int j = beg; j < end; ++j) {
        float w = __expf(wei[(size_t)j * 8 + hd] - m);
        ssum += w;
        wei[(size_t)j * 8 + hd] = w;
    }
    invs[i] = 1.f / (ssum + 1e-16f);
}

// one thread per node (layer 2, H=1)
__global__ void k_wei2(const float* __restrict__ asrc, const float* __restrict__ adst,
                       const int* __restrict__ rowptr, const int* __restrict__ col,
                       float* __restrict__ wei, float* __restrict__ invs, int n) {
    int i = blockIdx.x * blockDim.x + threadIdx.x;
    if (i >= n) return;
    int beg = rowptr[i], end = rowptr[i + 1];
    float ad = adst[i];
    float m = -1e30f;
    for (int j = beg; j < end; ++j) {
        int s = col[j];
        float e = asrc[s] + ad;
        e = (e >= 0.f) ? e : 0.2f * e;
        wei[j] = e;
        m = fmaxf(m, e);
    }
    float ssum = 0.f;
    for (int j = beg; j < end; ++j) {
        float w = __expf(wei[j] - m);
        ssum += w;
        wei[j] = w;
    }
    invs[i] = 1.f / (ssum + 1e-16f);
}

// ---------------- aggregation layers 0/1: one wave per node, 4 ch per lane ----------------
__global__ __launch_bounds__(256) void k_agg(const ushort* __restrict__ h,
                                             const float* __restrict__ wei,
                                             const float* __restrict__ invs,
                                             const int* __restrict__ rowptr,
                                             const int* __restrict__ col,
                                             const float* __restrict__ bias,
                                             ushort* __restrict__ anext, int n) {
    int wid = threadIdx.x >> 6;
    int lane = threadIdx.x & 63;
    int node = blockIdx.x * 4 + wid;
    if (node >= n) return;
    int beg = rowptr[node], end = rowptr[node + 1];
    int hd = lane >> 3;           // = (lane*4)>>5
    float a0 = 0.f, a1 = 0.f, a2 = 0.f, a3 = 0.f;
    for (int j = beg; j < end; ++j) {
        int s = col[j];
        float w = wei[(size_t)j * 8 + hd];
        us4 hv = *(const us4*)(h + (size_t)s * 256 + lane * 4);
        a0 += w * bf2f(hv[0]);
        a1 += w * bf2f(hv[1]);
        a2 += w * bf2f(hv[2]);
        a3 += w * bf2f(hv[3]);
    }
    float inv = invs[node * 8 + hd];
    f32x4 bv = *(const f32x4*)(bias + lane * 4);
    float v0 = a0 * inv + bv[0];
    float v1 = a1 * inv + bv[1];
    float v2 = a2 * inv + bv[2];
    float v3 = a3 * inv + bv[3];
    v0 = (v0 > 0.f) ? v0 : expm1f(v0);
    v1 = (v1 > 0.f) ? v1 : expm1f(v1);
    v2 = (v2 > 0.f) ? v2 : expm1f(v2);
    v3 = (v3 > 0.f) ? v3 : expm1f(v3);
    us4 o;
    o[0] = f2bf(v0); o[1] = f2bf(v1); o[2] = f2bf(v2); o[3] = f2bf(v3);
    *(us4*)(anext + (size_t)node * 256 + lane * 4) = o;
}

// ---------------- aggregation layer 2 + bias + log_softmax: one wave per node ----------------
__global__ __launch_bounds__(256) void k_agg2(const float* __restrict__ h2,
                                              const float* __restrict__ wei,
                                              const float* __restrict__ invs,
                                              const int* __restrict__ rowptr,
                                              const int* __restrict__ col,
                                              const float* __restrict__ bias,
                                              float* __restrict__ out, int n) {
    int wid = threadIdx.x >> 6;
    int lane = threadIdx.x & 63;
    int node = blockIdx.x * 4 + wid;
    if (node >= n) return;
    int beg = rowptr[node], end = rowptr[node + 1];
    float acc = 0.f;
    for (int j = beg; j < end; ++j) {
        int s = col[j];
        float w = wei[j];
        acc += w * h2[(size_t)s * 64 + lane];
    }
    float v = acc * invs[node] + bias[lane];
    float mx = v;
#pragma unroll
    for (int off = 32; off > 0; off >>= 1) mx = fmaxf(mx, __shfl_xor(mx, off));
    float ex = __expf(v - mx);
    float se = ex;
#pragma unroll
    for (int off = 32; off > 0; off >>= 1) se += __shfl_xor(se, off);
    out[(size_t)node * 64 + lane] = v - mx - logf(se);
}

extern "C" void kernel_launch(void* const* d_in, const int* in_sizes, int n_in,
                              void* d_out, int out_size, void* d_ws, size_t ws_size,
                              hipStream_t stream) {
    const float* x   = (const float*)d_in[0];
    const int*   ei  = (const int*)d_in[1];
    const float* W0  = (const float*)d_in[2];
    const float* as0 = (const float*)d_in[3];
    const float* ad0 = (const float*)d_in[4];
    const float* b0  = (const float*)d_in[5];
    const float* W1  = (const float*)d_in[6];
    const float* as1 = (const float*)d_in[7];
    const float* ad1 = (const float*)d_in[8];
    const float* b1  = (const float*)d_in[9];
    const float* W2  = (const float*)d_in[10];
    const float* as2 = (const float*)d_in[11];
    const float* ad2 = (const float*)d_in[12];
    const float* b2  = (const float*)d_in[13];
    float* out = (float*)d_out;

    const int N = in_sizes[0] / 512;   // 50000
    const int E = in_sizes[1] / 2;     // 800000
    const int ETOT = E + N;

    char* ws = (char*)d_ws;
    size_t off = 0;
    auto alloc = [&](size_t bytes) -> void* {
        off = (off + 255) & ~(size_t)255;
        void* p = ws + off;
        off += bytes;
        return p;
    };
    int* rowptr = (int*)alloc((size_t)(N + 1) * 4);
    int* cursor = (int*)alloc((size_t)N * 4);
    int* deg    = (int*)alloc((size_t)N * 4);
    int* bsum   = (int*)alloc(1024);
    int* boff   = (int*)alloc(1024);
    int* colb   = (int*)alloc((size_t)ETOT * 4);
    ushort* WT0 = (ushort*)alloc((size_t)256 * 512 * 2);
    ushort* WT1 = (ushort*)alloc((size_t)256 * 256 * 2);
    ushort* WT2 = (ushort*)alloc((size_t)64 * 256 * 2);
    ushort* hbf = (ushort*)alloc((size_t)N * 256 * 2);
    ushort* abf = (ushort*)alloc((size_t)N * 256 * 2);
    float* asrc = (float*)alloc((size_t)N * 8 * 4);
    float* adst = (float*)alloc((size_t)N * 8 * 4);
    float* wei  = (float*)alloc((size_t)ETOT * 8 * 4);
    float* invs = (float*)alloc((size_t)N * 8 * 4);
    // aliases (lifetimes disjoint)
    float* h2    = (float*)hbf;           // layer-2 gemm output (12.8MB <= 25.6MB)
    float* asrc2 = asrc;
    float* adst2 = adst;
    float* wei2  = wei;
    float* invs2 = invs;

    const int nblk = (N + 255) / 256;  // 196

    // CSR build
    k_deg_init<<<(N + 255) / 256, 256, 0, stream>>>(deg, N);
    k_hist<<<(E + 255) / 256, 256, 0, stream>>>(ei + E, deg, E);
    k_scanA<<<nblk, 256, 0, stream>>>(deg, bsum, N);
    k_scanB<<<1, 256, 0, stream>>>(bsum, boff, nblk);
    k_scanC<<<nblk, 256, 0, stream>>>(deg, boff, rowptr, cursor, N, ETOT);
    k_scatter<<<(ETOT + 255) / 256, 256, 0, stream>>>(ei, cursor, colb, E, N);

    // weights
    k_wcvt<<<(512 * 256 + 255) / 256, 256, 0, stream>>>(W0, WT0, 512, 256);
    k_wcvt<<<(256 * 256 + 255) / 256, 256, 0, stream>>>(W1, WT1, 256, 256);
    k_wcvt<<<(256 * 64 + 255) / 256, 256, 0, stream>>>(W2, WT2, 256, 64);

    const int gblk = (N + 63) / 64;   // 782
    const int ablk = (N + 3) / 4;     // 12500

    // layer 0
    k_gemm<512, 16, true, true><<<gblk, 256, 0, stream>>>(x, WT0, hbf, N);
    k_alpha<<<(N * 8 + 255) / 256, 256, 0, stream>>>(hbf, as0, ad0, asrc, adst, N);
    k_wei<<<(N * 8 + 255) / 256, 256, 0, stream>>>(asrc, adst, rowptr, colb, wei, invs, N);
    k_agg<<<ablk, 256, 0, stream>>>(hbf, wei, invs, rowptr, colb, b0, abf, N);

    // layer 1
    k_gemm<256, 16, false, true><<<gblk, 256, 0, stream>>>(abf, WT1, hbf, N);
    k_alpha<<<(N * 8 + 255) / 256, 256, 0, stream>>>(hbf, as1, ad1, asrc, adst, N);
    k_wei<<<(N * 8 + 255) / 256, 256, 0, stream>>>(asrc, adst, rowptr, colb, wei, invs, N);
    k_agg<<<ablk, 256, 0, stream>>>(hbf, wei, invs, rowptr, colb, b1, abf, N);

    // layer 2
    k_gemm<256, 4, false, false><<<gblk, 256, 0, stream>>>(abf, WT2, h2, N);
    k_alpha2<<<(N + 255) / 256, 256, 0, stream>>>(h2, as2, ad2, asrc2, adst2, N);
    k_wei2<<<(N + 255) / 256, 256, 0, stream>>>(asrc2, adst2, rowptr, colb, wei2, invs2, N);
    k_agg2<<<ablk, 256, 0, stream>>>(h2, wei2, invs2, rowptr, colb, b2, out, N);
}

// Round 3
// 587.037 us; speedup vs baseline: 1.8342x; 1.2988x over previous
//
#include <hip/hip_runtime.h>
#include <hip/hip_bf16.h>

typedef __attribute__((ext_vector_type(8))) short short8;
typedef __attribute__((ext_vector_type(4))) float f32x4;
typedef __attribute__((ext_vector_type(4))) unsigned short us4;

__device__ __forceinline__ ushort f2bf(float f) {
    unsigned u = __float_as_uint(f);
    u += 0x7FFFu + ((u >> 16) & 1u);
    return (ushort)(u >> 16);
}
__device__ __forceinline__ float bf2f(ushort h) {
    return __uint_as_float(((unsigned)h) << 16);
}
__device__ __forceinline__ void gload16(const void* g, void* l) {
    __builtin_amdgcn_global_load_lds(
        (const __attribute__((address_space(1))) unsigned int*)g,
        (__attribute__((address_space(3))) unsigned int*)l, 16, 0, 0);
}

// ---------------- CSR build ----------------
__global__ void k_deg_init(int* deg, int n) {
    int i = blockIdx.x * blockDim.x + threadIdx.x;
    if (i < n) deg[i] = 1;  // self loop
}
__global__ void k_hist(const int* __restrict__ dst, int* __restrict__ deg, int e) {
    int i = blockIdx.x * blockDim.x + threadIdx.x;
    if (i < e) atomicAdd(&deg[dst[i]], 1);
}
__global__ void k_scanA(const int* __restrict__ deg, int* __restrict__ bsum, int n) {
    __shared__ int sd[256];
    int t = blockIdx.x * 256 + threadIdx.x;
    sd[threadIdx.x] = (t < n) ? deg[t] : 0;
    __syncthreads();
    for (int off = 128; off > 0; off >>= 1) {
        if (threadIdx.x < off) sd[threadIdx.x] += sd[threadIdx.x + off];
        __syncthreads();
    }
    if (threadIdx.x == 0) bsum[blockIdx.x] = sd[0];
}
__global__ void k_scanB(const int* __restrict__ bsum, int* __restrict__ boff, int nb) {
    __shared__ int sd[256];
    int i = threadIdx.x;
    int v = (i < nb) ? bsum[i] : 0;
    sd[i] = v;
    __syncthreads();
    for (int off = 1; off < 256; off <<= 1) {
        int t = (i >= off) ? sd[i - off] : 0;
        __syncthreads();
        sd[i] += t;
        __syncthreads();
    }
    if (i < nb) boff[i] = sd[i] - v;  // exclusive
}
__global__ void k_scanC(const int* __restrict__ deg, const int* __restrict__ boff,
                        int* __restrict__ rowptr, int* __restrict__ cursor, int n, int etot) {
    __shared__ int sd[256];
    int t = blockIdx.x * 256 + threadIdx.x;
    int i = threadIdx.x;
    int v = (t < n) ? deg[t] : 0;
    sd[i] = v;
    __syncthreads();
    for (int off = 1; off < 256; off <<= 1) {
        int tv = (i >= off) ? sd[i - off] : 0;
        __syncthreads();
        sd[i] += tv;
        __syncthreads();
    }
    if (t < n) {
        int ex = boff[blockIdx.x] + sd[i] - v;
        rowptr[t] = ex;
        cursor[t] = ex;
        if (t == n - 1) rowptr[n] = etot;
    }
}
__global__ void k_scatter(const int* __restrict__ ei, int* __restrict__ cursor,
                          int* __restrict__ col, int e, int n) {
    int i = blockIdx.x * blockDim.x + threadIdx.x;
    int etot = e + n;
    if (i >= etot) return;
    int s, d;
    if (i < e) { s = ei[i]; d = ei[e + i]; }
    else       { s = i - e; d = s; }
    int pos = atomicAdd(&cursor[d], 1);
    col[pos] = s;
}

// ---------------- weight transpose + bf16 cvt ----------------
__global__ void k_wcvt(const float* __restrict__ W, ushort* __restrict__ WT, int K, int Nc) {
    int i = blockIdx.x * blockDim.x + threadIdx.x;
    if (i < K * Nc) {
        int k = i / Nc, c = i % Nc;
        WT[(size_t)c * K + k] = f2bf(W[i]);
    }
}

// ---------------- GEMM: C[M,Nc] = A[M,K] x B, B given as BT[Nc][K] bf16 ----------------
// BM=128, BK=32, double-buffered LDS, global_load_lds staging, 4 waves each 64 x BN/2.
// k-slot XOR swizzle (kslot ^ (row>>1)&3) applied identically on stage-src and ds_read.
template <int K, int BN, bool AF32, bool STORE_BF>
__global__ __launch_bounds__(256) void k_gemm(const void* __restrict__ Ap,
                                              const ushort* __restrict__ BT,
                                              void* __restrict__ Cp, int M) {
    constexpr int BM = 128, BK = 32;
    constexpr int NK = K / BK;
    constexpr int NF = BN / 32;           // n-frags per wave
    constexpr int AU = BM * BK / 8;       // 512 16B-units in A tile
    constexpr int BU = BN * BK / 8;       // 16B-units in B tile
    constexpr int TU = AU + BU;
    __shared__ __align__(16) ushort lds[2][TU * 8];

    const int t = threadIdx.x;
    const int wid = t >> 6, lane = t & 63;
    const int lr = lane & 15, lg = lane >> 4;
    const int wm = wid >> 1, wn = wid & 1;
    const int bm0 = blockIdx.x * BM;
    const int bn0 = blockIdx.y * BN;
    const int Nc = BN * gridDim.y;

    // precomputed frag LDS byte offsets (within one buffer)
    int a_off[4], b_off[NF];
#pragma unroll
    for (int mf = 0; mf < 4; ++mf) {
        int row = wm * 64 + mf * 16 + lr;
        a_off[mf] = row * 64 + ((lg ^ ((row >> 1) & 3)) << 4);
    }
#pragma unroll
    for (int nf = 0; nf < NF; ++nf) {
        int col = wn * (BN / 2) + nf * 16 + lr;
        b_off[nf] = AU * 16 + col * 64 + ((lg ^ ((col >> 1) & 3)) << 4);
    }

    f32x4 acc[4][NF];
#pragma unroll
    for (int mf = 0; mf < 4; ++mf)
#pragma unroll
        for (int nf = 0; nf < NF; ++nf) acc[mf][nf] = f32x4{0.f, 0.f, 0.f, 0.f};

    f32x4 ra[2][2];  // f32 A staging regs (AF32 path)

    auto stage_B = [&](int buf, int kk) {
#pragma unroll
        for (int i = 0; i < BU / 256; ++i) {
            int u = t + i * 256;
            int col = u >> 2;
            int g = (u & 3) ^ ((col >> 1) & 3);
            const ushort* src = BT + (size_t)(bn0 + col) * K + kk + g * 8;
            gload16(src, &lds[buf][(AU + u) * 8]);
        }
    };
    auto stage_A16 = [&](int buf, int kk) {
#pragma unroll
        for (int i = 0; i < 2; ++i) {
            int u = t + i * 256;
            int row = u >> 2;
            int g = (u & 3) ^ ((row >> 1) & 3);
            int grow = bm0 + row;
            if (grow >= M) grow = M - 1;
            const ushort* src = (const ushort*)Ap + (size_t)grow * K + kk + g * 8;
            gload16(src, &lds[buf][u * 8]);
        }
    };
    auto load_A32 = [&](int kk) {
#pragma unroll
        for (int i = 0; i < 2; ++i) {
            int u = t + i * 256;
            int row = u >> 2;
            int g = (u & 3) ^ ((row >> 1) & 3);
            int grow = bm0 + row;
            if (grow >= M) grow = M - 1;
            const float* src = (const float*)Ap + (size_t)grow * K + kk + g * 8;
            ra[i][0] = *(const f32x4*)src;
            ra[i][1] = *(const f32x4*)(src + 4);
        }
    };
    auto write_A32 = [&](int buf) {
#pragma unroll
        for (int i = 0; i < 2; ++i) {
            int u = t + i * 256;
            short8 v;
#pragma unroll
            for (int j = 0; j < 4; ++j) {
                v[j] = (short)f2bf(ra[i][0][j]);
                v[4 + j] = (short)f2bf(ra[i][1][j]);
            }
            *(short8*)&lds[buf][u * 8] = v;
        }
    };
    auto compute = [&](int buf) {
        const char* base = (const char*)lds[buf];
        short8 af[4], bf_[NF];
#pragma unroll
        for (int mf = 0; mf < 4; ++mf) af[mf] = *(const short8*)(base + a_off[mf]);
#pragma unroll
        for (int nf = 0; nf < NF; ++nf) bf_[nf] = *(const short8*)(base + b_off[nf]);
#pragma unroll
        for (int mf = 0; mf < 4; ++mf)
#pragma unroll
            for (int nf = 0; nf < NF; ++nf)
                acc[mf][nf] = __builtin_amdgcn_mfma_f32_16x16x32_bf16(af[mf], bf_[nf], acc[mf][nf], 0, 0, 0);
    };

    // prologue: stage tile 0
    if constexpr (AF32) {
        load_A32(0);
        write_A32(0);
    } else {
        stage_A16(0, 0);
    }
    stage_B(0, 0);
    __syncthreads();

    int buf = 0;
    for (int ks = 0; ks < NK; ++ks) {
        const int kk = (ks + 1) * BK;
        if (ks + 1 < NK) {
            if constexpr (AF32) load_A32(kk);
            else stage_A16(buf ^ 1, kk);
            stage_B(buf ^ 1, kk);
        }
        compute(buf);
        if constexpr (AF32) {
            if (ks + 1 < NK) write_A32(buf ^ 1);
        }
        __syncthreads();
        buf ^= 1;
    }

    // epilogue
#pragma unroll
    for (int mf = 0; mf < 4; ++mf) {
#pragma unroll
        for (int nf = 0; nf < NF; ++nf) {
            int col = bn0 + wn * (BN / 2) + nf * 16 + lr;
#pragma unroll
            for (int p = 0; p < 4; ++p) {
                int row = bm0 + wm * 64 + mf * 16 + lg * 4 + p;
                if (row < M) {
                    if (STORE_BF)
                        ((ushort*)Cp)[(size_t)row * Nc + col] = f2bf(acc[mf][nf][p]);
                    else
                        ((float*)Cp)[(size_t)row * Nc + col] = acc[mf][nf][p];
                }
            }
        }
    }
}

// ---------------- attention coefficients (vectorized) ----------------
__global__ void k_alpha(const ushort* __restrict__ h, const float* __restrict__ a_src,
                        const float* __restrict__ a_dst, float* __restrict__ asrc,
                        float* __restrict__ adst, int n) {
    int i = blockIdx.x * blockDim.x + threadIdx.x;
    if (i >= n * 8) return;
    int node = i >> 3, hd = i & 7;
    const ushort* hp = h + (size_t)node * 256 + hd * 32;
    const float* as = a_src + hd * 32;
    const float* ad = a_dst + hd * 32;
    float s1 = 0.f, s2 = 0.f;
#pragma unroll
    for (int c = 0; c < 4; ++c) {
        short8 hv = *(const short8*)(hp + c * 8);
#pragma unroll
        for (int j = 0; j < 8; ++j) {
            float v = bf2f((ushort)hv[j]);
            s1 += v * as[c * 8 + j];
            s2 += v * ad[c * 8 + j];
        }
    }
    asrc[i] = s1;
    adst[i] = s2;
}
__global__ void k_alpha2(const float* __restrict__ h2, const float* __restrict__ a_src,
                         const float* __restrict__ a_dst, float* __restrict__ asrc,
                         float* __restrict__ adst, int n) {
    int i = blockIdx.x * blockDim.x + threadIdx.x;
    if (i >= n) return;
    const float* hp = h2 + (size_t)i * 64;
    float s1 = 0.f, s2 = 0.f;
#pragma unroll
    for (int j = 0; j < 64; ++j) {
        float v = hp[j];
        s1 += v * a_src[j];
        s2 += v * a_dst[j];
    }
    asrc[i] = s1;
    adst[i] = s2;
}

// ---------------- softmax weights: one thread per (node, head) ----------------
__global__ void k_wei(const float* __restrict__ asrc, const float* __restrict__ adst,
                      const int* __restrict__ rowptr, const int* __restrict__ col,
                      float* __restrict__ wei, float* __restrict__ invs, int n) {
    int i = blockIdx.x * blockDim.x + threadIdx.x;
    if (i >= n * 8) return;
    int node = i >> 3, hd = i & 7;
    int beg = rowptr[node], end = rowptr[node + 1];
    float ad = adst[i];
    float m = -1e30f;
    for (int j = beg; j < end; ++j) {
        int s = col[j];
        float e = asrc[s * 8 + hd] + ad;
        e = (e >= 0.f) ? e : 0.2f * e;
        wei[(size_t)j * 8 + hd] = e;
        m = fmaxf(m, e);
    }
    float ssum = 0.f;
    for (int j = beg; j < end; ++j) {
        float w = __expf(wei[(size_t)j * 8 + hd] - m);
        ssum += w;
        wei[(size_t)j * 8 + hd] = w;
    }
    invs[i] = 1.f / (ssum + 1e-16f);
}
__global__ void k_wei2(const float* __restrict__ asrc, const float* __restrict__ adst,
                       const int* __restrict__ rowptr, const int* __restrict__ col,
                       float* __restrict__ wei, float* __restrict__ invs, int n) {
    int i = blockIdx.x * blockDim.x + threadIdx.x;
    if (i >= n) return;
    int beg = rowptr[i], end = rowptr[i + 1];
    float ad = adst[i];
    float m = -1e30f;
    for (int j = beg; j < end; ++j) {
        int s = col[j];
        float e = asrc[s] + ad;
        e = (e >= 0.f) ? e : 0.2f * e;
        wei[j] = e;
        m = fmaxf(m, e);
    }
    float ssum = 0.f;
    for (int j = beg; j < end; ++j) {
        float w = __expf(wei[j] - m);
        ssum += w;
        wei[j] = w;
    }
    invs[i] = 1.f / (ssum + 1e-16f);
}

// ---------------- aggregation layers 0/1: one wave per node, 4 ch per lane ----------------
__global__ __launch_bounds__(256) void k_agg(const ushort* __restrict__ h,
                                             const float* __restrict__ wei,
                                             const float* __restrict__ invs,
                                             const int* __restrict__ rowptr,
                                             const int* __restrict__ col,
                                             const float* __restrict__ bias,
                                             ushort* __restrict__ anext, int n) {
    int wid = threadIdx.x >> 6;
    int lane = threadIdx.x & 63;
    int node = blockIdx.x * 4 + wid;
    if (node >= n) return;
    int beg = rowptr[node], end = rowptr[node + 1];
    int hd = lane >> 3;
    float a0 = 0.f, a1 = 0.f, a2 = 0.f, a3 = 0.f;
    for (int j = beg; j < end; ++j) {
        int s = col[j];
        float w = wei[(size_t)j * 8 + hd];
        us4 hv = *(const us4*)(h + (size_t)s * 256 + lane * 4);
        a0 += w * bf2f(hv[0]);
        a1 += w * bf2f(hv[1]);
        a2 += w * bf2f(hv[2]);
        a3 += w * bf2f(hv[3]);
    }
    float inv = invs[node * 8 + hd];
    f32x4 bv = *(const f32x4*)(bias + lane * 4);
    float v0 = a0 * inv + bv[0];
    float v1 = a1 * inv + bv[1];
    float v2 = a2 * inv + bv[2];
    float v3 = a3 * inv + bv[3];
    v0 = (v0 > 0.f) ? v0 : expm1f(v0);
    v1 = (v1 > 0.f) ? v1 : expm1f(v1);
    v2 = (v2 > 0.f) ? v2 : expm1f(v2);
    v3 = (v3 > 0.f) ? v3 : expm1f(v3);
    us4 o;
    o[0] = f2bf(v0); o[1] = f2bf(v1); o[2] = f2bf(v2); o[3] = f2bf(v3);
    *(us4*)(anext + (size_t)node * 256 + lane * 4) = o;
}

// ---------------- aggregation layer 2 + bias + log_softmax: one wave per node ----------------
__global__ __launch_bounds__(256) void k_agg2(const float* __restrict__ h2,
                                              const float* __restrict__ wei,
                                              const float* __restrict__ invs,
                                              const int* __restrict__ rowptr,
                                              const int* __restrict__ col,
                                              const float* __restrict__ bias,
                                              float* __restrict__ out, int n) {
    int wid = threadIdx.x >> 6;
    int lane = threadIdx.x & 63;
    int node = blockIdx.x * 4 + wid;
    if (node >= n) return;
    int beg = rowptr[node], end = rowptr[node + 1];
    float acc = 0.f;
    for (int j = beg; j < end; ++j) {
        int s = col[j];
        acc += wei[j] * h2[(size_t)s * 64 + lane];
    }
    float v = acc * invs[node] + bias[lane];
    float mx = v;
#pragma unroll
    for (int off = 32; off > 0; off >>= 1) mx = fmaxf(mx, __shfl_xor(mx, off));
    float ex = __expf(v - mx);
    float se = ex;
#pragma unroll
    for (int off = 32; off > 0; off >>= 1) se += __shfl_xor(se, off);
    out[(size_t)node * 64 + lane] = v - mx - logf(se);
}

extern "C" void kernel_launch(void* const* d_in, const int* in_sizes, int n_in,
                              void* d_out, int out_size, void* d_ws, size_t ws_size,
                              hipStream_t stream) {
    const float* x   = (const float*)d_in[0];
    const int*   ei  = (const int*)d_in[1];
    const float* W0  = (const float*)d_in[2];
    const float* as0 = (const float*)d_in[3];
    const float* ad0 = (const float*)d_in[4];
    const float* b0  = (const float*)d_in[5];
    const float* W1  = (const float*)d_in[6];
    const float* as1 = (const float*)d_in[7];
    const float* ad1 = (const float*)d_in[8];
    const float* b1  = (const float*)d_in[9];
    const float* W2  = (const float*)d_in[10];
    const float* as2 = (const float*)d_in[11];
    const float* ad2 = (const float*)d_in[12];
    const float* b2  = (const float*)d_in[13];
    float* out = (float*)d_out;

    const int N = in_sizes[0] / 512;   // 50000
    const int E = in_sizes[1] / 2;     // 800000
    const int ETOT = E + N;

    char* ws = (char*)d_ws;
    size_t off = 0;
    auto alloc = [&](size_t bytes) -> void* {
        off = (off + 255) & ~(size_t)255;
        void* p = ws + off;
        off += bytes;
        return p;
    };
    int* rowptr = (int*)alloc((size_t)(N + 1) * 4);
    int* cursor = (int*)alloc((size_t)N * 4);
    int* deg    = (int*)alloc((size_t)N * 4);
    int* bsum   = (int*)alloc(1024);
    int* boff   = (int*)alloc(1024);
    int* colb   = (int*)alloc((size_t)ETOT * 4);
    ushort* WT0 = (ushort*)alloc((size_t)256 * 512 * 2);
    ushort* WT1 = (ushort*)alloc((size_t)256 * 256 * 2);
    ushort* WT2 = (ushort*)alloc((size_t)64 * 256 * 2);
    ushort* hbf = (ushort*)alloc((size_t)N * 256 * 2);
    ushort* abf = (ushort*)alloc((size_t)N * 256 * 2);
    float* asrc = (float*)alloc((size_t)N * 8 * 4);
    float* adst = (float*)alloc((size_t)N * 8 * 4);
    float* wei  = (float*)alloc((size_t)ETOT * 8 * 4);
    float* invs = (float*)alloc((size_t)N * 8 * 4);
    // aliases (lifetimes disjoint)
    float* h2    = (float*)hbf;
    float* asrc2 = asrc;
    float* adst2 = adst;
    float* wei2  = wei;
    float* invs2 = invs;

    const int nblk = (N + 255) / 256;  // 196

    // CSR build
    k_deg_init<<<(N + 255) / 256, 256, 0, stream>>>(deg, N);
    k_hist<<<(E + 255) / 256, 256, 0, stream>>>(ei + E, deg, E);
    k_scanA<<<nblk, 256, 0, stream>>>(deg, bsum, N);
    k_scanB<<<1, 256, 0, stream>>>(bsum, boff, nblk);
    k_scanC<<<nblk, 256, 0, stream>>>(deg, boff, rowptr, cursor, N, ETOT);
    k_scatter<<<(ETOT + 255) / 256, 256, 0, stream>>>(ei, cursor, colb, E, N);

    // weights
    k_wcvt<<<(512 * 256 + 255) / 256, 256, 0, stream>>>(W0, WT0, 512, 256);
    k_wcvt<<<(256 * 256 + 255) / 256, 256, 0, stream>>>(W1, WT1, 256, 256);
    k_wcvt<<<(256 * 64 + 255) / 256, 256, 0, stream>>>(W2, WT2, 256, 64);

    const dim3 g01((N + 127) / 128, 2);  // 391 x 2
    const dim3 g2 ((N + 127) / 128, 1);  // 391 x 1
    const int ablk = (N + 3) / 4;        // 12500

    // layer 0
    k_gemm<512, 128, true, true><<<g01, 256, 0, stream>>>(x, WT0, hbf, N);
    k_alpha<<<(N * 8 + 255) / 256, 256, 0, stream>>>(hbf, as0, ad0, asrc, adst, N);
    k_wei<<<(N * 8 + 255) / 256, 256, 0, stream>>>(asrc, adst, rowptr, colb, wei, invs, N);
    k_agg<<<ablk, 256, 0, stream>>>(hbf, wei, invs, rowptr, colb, b0, abf, N);

    // layer 1
    k_gemm<256, 128, false, true><<<g01, 256, 0, stream>>>(abf, WT1, hbf, N);
    k_alpha<<<(N * 8 + 255) / 256, 256, 0, stream>>>(hbf, as1, ad1, asrc, adst, N);
    k_wei<<<(N * 8 + 255) / 256, 256, 0, stream>>>(asrc, adst, rowptr, colb, wei, invs, N);
    k_agg<<<ablk, 256, 0, stream>>>(hbf, wei, invs, rowptr, colb, b1, abf, N);

    // layer 2
    k_gemm<256, 64, false, false><<<g2, 256, 0, stream>>>(abf, WT2, h2, N);
    k_alpha2<<<(N + 255) / 256, 256, 0, stream>>>(h2, as2, ad2, asrc2, adst2, N);
    k_wei2<<<(N + 255) / 256, 256, 0, stream>>>(asrc2, adst2, rowptr, colb, wei2, invs2, N);
    k_agg2<<<ablk, 256, 0, stream>>>(h2, wei2, invs2, rowptr, colb, b2, out, N);
}

// Round 4
// 436.568 us; speedup vs baseline: 2.4663x; 1.3447x over previous
//
#include <hip/hip_runtime.h>
#include <hip/hip_bf16.h>

typedef __attribute__((ext_vector_type(8))) short short8;
typedef __attribute__((ext_vector_type(4))) float f32x4;
typedef __attribute__((ext_vector_type(4))) unsigned short us4;

__device__ __forceinline__ ushort f2bf(float f) {
    unsigned u = __float_as_uint(f);
    u += 0x7FFFu + ((u >> 16) & 1u);
    return (ushort)(u >> 16);
}
__device__ __forceinline__ float bf2f(ushort h) {
    return __uint_as_float(((unsigned)h) << 16);
}
__device__ __forceinline__ float lrelu(float e) { return (e >= 0.f) ? e : 0.2f * e; }
__device__ __forceinline__ void gload16(const void* g, void* l) {
    __builtin_amdgcn_global_load_lds(
        (const __attribute__((address_space(1))) unsigned int*)g,
        (__attribute__((address_space(3))) unsigned int*)l, 16, 0, 0);
}

// ---------------- CSR build ----------------
__global__ void k_deg_init(int* deg, int n) {
    int i = blockIdx.x * blockDim.x + threadIdx.x;
    if (i < n) deg[i] = 1;  // self loop
}
__global__ void k_hist(const int* __restrict__ dst, int* __restrict__ deg, int e) {
    int i = blockIdx.x * blockDim.x + threadIdx.x;
    if (i < e) atomicAdd(&deg[dst[i]], 1);
}
__global__ void k_scanA(const int* __restrict__ deg, int* __restrict__ bsum, int n) {
    __shared__ int sd[256];
    int t = blockIdx.x * 256 + threadIdx.x;
    sd[threadIdx.x] = (t < n) ? deg[t] : 0;
    __syncthreads();
    for (int off = 128; off > 0; off >>= 1) {
        if (threadIdx.x < off) sd[threadIdx.x] += sd[threadIdx.x + off];
        __syncthreads();
    }
    if (threadIdx.x == 0) bsum[blockIdx.x] = sd[0];
}
__global__ void k_scanB(const int* __restrict__ bsum, int* __restrict__ boff, int nb) {
    __shared__ int sd[256];
    int i = threadIdx.x;
    int v = (i < nb) ? bsum[i] : 0;
    sd[i] = v;
    __syncthreads();
    for (int off = 1; off < 256; off <<= 1) {
        int t = (i >= off) ? sd[i - off] : 0;
        __syncthreads();
        sd[i] += t;
        __syncthreads();
    }
    if (i < nb) boff[i] = sd[i] - v;  // exclusive
}
__global__ void k_scanC(const int* __restrict__ deg, const int* __restrict__ boff,
                        int* __restrict__ rowptr, int* __restrict__ cursor, int n, int etot) {
    __shared__ int sd[256];
    int t = blockIdx.x * 256 + threadIdx.x;
    int i = threadIdx.x;
    int v = (t < n) ? deg[t] : 0;
    sd[i] = v;
    __syncthreads();
    for (int off = 1; off < 256; off <<= 1) {
        int tv = (i >= off) ? sd[i - off] : 0;
        __syncthreads();
        sd[i] += tv;
        __syncthreads();
    }
    if (t < n) {
        int ex = boff[blockIdx.x] + sd[i] - v;
        rowptr[t] = ex;
        cursor[t] = ex;
        if (t == n - 1) rowptr[n] = etot;
    }
}
__global__ void k_scatter(const int* __restrict__ ei, int* __restrict__ cursor,
                          int* __restrict__ col, int e, int n) {
    int i = blockIdx.x * blockDim.x + threadIdx.x;
    int etot = e + n;
    if (i >= etot) return;
    int s, d;
    if (i < e) { s = ei[i]; d = ei[e + i]; }
    else       { s = i - e; d = s; }
    int pos = atomicAdd(&cursor[d], 1);
    col[pos] = s;
}

// ---------------- weight transpose + bf16 cvt ----------------
__global__ void k_wcvt(const float* __restrict__ W, ushort* __restrict__ WT, int K, int Nc) {
    int i = blockIdx.x * blockDim.x + threadIdx.x;
    if (i < K * Nc) {
        int k = i / Nc, c = i % Nc;
        WT[(size_t)c * K + k] = f2bf(W[i]);
    }
}

// ---------------- GEMM: C[M,Nc] = A[M,K] x B, B given as BT[Nc][K] bf16 ----------------
template <int K, int BN, bool AF32, bool STORE_BF>
__global__ __launch_bounds__(256) void k_gemm(const void* __restrict__ Ap,
                                              const ushort* __restrict__ BT,
                                              void* __restrict__ Cp, int M) {
    constexpr int BM = 128, BK = 32;
    constexpr int NK = K / BK;
    constexpr int NF = BN / 32;
    constexpr int AU = BM * BK / 8;
    constexpr int BU = BN * BK / 8;
    constexpr int TU = AU + BU;
    __shared__ __align__(16) ushort lds[2][TU * 8];

    const int t = threadIdx.x;
    const int wid = t >> 6, lane = t & 63;
    const int lr = lane & 15, lg = lane >> 4;
    const int wm = wid >> 1, wn = wid & 1;
    const int bm0 = blockIdx.x * BM;
    const int bn0 = blockIdx.y * BN;
    const int Nc = BN * gridDim.y;

    int a_off[4], b_off[NF];
#pragma unroll
    for (int mf = 0; mf < 4; ++mf) {
        int row = wm * 64 + mf * 16 + lr;
        a_off[mf] = row * 64 + ((lg ^ ((row >> 1) & 3)) << 4);
    }
#pragma unroll
    for (int nf = 0; nf < NF; ++nf) {
        int col = wn * (BN / 2) + nf * 16 + lr;
        b_off[nf] = AU * 16 + col * 64 + ((lg ^ ((col >> 1) & 3)) << 4);
    }

    f32x4 acc[4][NF];
#pragma unroll
    for (int mf = 0; mf < 4; ++mf)
#pragma unroll
        for (int nf = 0; nf < NF; ++nf) acc[mf][nf] = f32x4{0.f, 0.f, 0.f, 0.f};

    f32x4 ra[2][2];

    auto stage_B = [&](int buf, int kk) {
#pragma unroll
        for (int i = 0; i < BU / 256; ++i) {
            int u = t + i * 256;
            int col = u >> 2;
            int g = (u & 3) ^ ((col >> 1) & 3);
            const ushort* src = BT + (size_t)(bn0 + col) * K + kk + g * 8;
            gload16(src, &lds[buf][(AU + u) * 8]);
        }
    };
    auto stage_A16 = [&](int buf, int kk) {
#pragma unroll
        for (int i = 0; i < 2; ++i) {
            int u = t + i * 256;
            int row = u >> 2;
            int g = (u & 3) ^ ((row >> 1) & 3);
            int grow = bm0 + row;
            if (grow >= M) grow = M - 1;
            const ushort* src = (const ushort*)Ap + (size_t)grow * K + kk + g * 8;
            gload16(src, &lds[buf][u * 8]);
        }
    };
    auto load_A32 = [&](int kk) {
#pragma unroll
        for (int i = 0; i < 2; ++i) {
            int u = t + i * 256;
            int row = u >> 2;
            int g = (u & 3) ^ ((row >> 1) & 3);
            int grow = bm0 + row;
            if (grow >= M) grow = M - 1;
            const float* src = (const float*)Ap + (size_t)grow * K + kk + g * 8;
            ra[i][0] = *(const f32x4*)src;
            ra[i][1] = *(const f32x4*)(src + 4);
        }
    };
    auto write_A32 = [&](int buf) {
#pragma unroll
        for (int i = 0; i < 2; ++i) {
            int u = t + i * 256;
            short8 v;
#pragma unroll
            for (int j = 0; j < 4; ++j) {
                v[j] = (short)f2bf(ra[i][0][j]);
                v[4 + j] = (short)f2bf(ra[i][1][j]);
            }
            *(short8*)&lds[buf][u * 8] = v;
        }
    };
    auto compute = [&](int buf) {
        const char* base = (const char*)lds[buf];
        short8 af[4], bf_[NF];
#pragma unroll
        for (int mf = 0; mf < 4; ++mf) af[mf] = *(const short8*)(base + a_off[mf]);
#pragma unroll
        for (int nf = 0; nf < NF; ++nf) bf_[nf] = *(const short8*)(base + b_off[nf]);
#pragma unroll
        for (int mf = 0; mf < 4; ++mf)
#pragma unroll
            for (int nf = 0; nf < NF; ++nf)
                acc[mf][nf] = __builtin_amdgcn_mfma_f32_16x16x32_bf16(af[mf], bf_[nf], acc[mf][nf], 0, 0, 0);
    };

    if constexpr (AF32) {
        load_A32(0);
        write_A32(0);
    } else {
        stage_A16(0, 0);
    }
    stage_B(0, 0);
    __syncthreads();

    int buf = 0;
    for (int ks = 0; ks < NK; ++ks) {
        const int kk = (ks + 1) * BK;
        if (ks + 1 < NK) {
            if constexpr (AF32) load_A32(kk);
            else stage_A16(buf ^ 1, kk);
            stage_B(buf ^ 1, kk);
        }
        compute(buf);
        if constexpr (AF32) {
            if (ks + 1 < NK) write_A32(buf ^ 1);
        }
        __syncthreads();
        buf ^= 1;
    }

#pragma unroll
    for (int mf = 0; mf < 4; ++mf) {
#pragma unroll
        for (int nf = 0; nf < NF; ++nf) {
            int col = bn0 + wn * (BN / 2) + nf * 16 + lr;
#pragma unroll
            for (int p = 0; p < 4; ++p) {
                int row = bm0 + wm * 64 + mf * 16 + lg * 4 + p;
                if (row < M) {
                    if (STORE_BF)
                        ((ushort*)Cp)[(size_t)row * Nc + col] = f2bf(acc[mf][nf][p]);
                    else
                        ((float*)Cp)[(size_t)row * Nc + col] = acc[mf][nf][p];
                }
            }
        }
    }
}

// ---------------- attention coefficients ----------------
__global__ void k_alpha(const ushort* __restrict__ h, const float* __restrict__ a_src,
                        const float* __restrict__ a_dst, float* __restrict__ asrc,
                        float* __restrict__ adst, int n) {
    int i = blockIdx.x * blockDim.x + threadIdx.x;
    if (i >= n * 8) return;
    int node = i >> 3, hd = i & 7;
    const ushort* hp = h + (size_t)node * 256 + hd * 32;
    const float* as = a_src + hd * 32;
    const float* ad = a_dst + hd * 32;
    float s1 = 0.f, s2 = 0.f;
#pragma unroll
    for (int c = 0; c < 4; ++c) {
        short8 hv = *(const short8*)(hp + c * 8);
#pragma unroll
        for (int j = 0; j < 8; ++j) {
            float v = bf2f((ushort)hv[j]);
            s1 += v * as[c * 8 + j];
            s2 += v * ad[c * 8 + j];
        }
    }
    asrc[i] = s1;
    adst[i] = s2;
}
__global__ void k_alpha2(const ushort* __restrict__ h2, const float* __restrict__ a_src,
                         const float* __restrict__ a_dst, float* __restrict__ asrc,
                         float* __restrict__ adst, int n) {
    int i = blockIdx.x * blockDim.x + threadIdx.x;
    if (i >= n) return;
    const ushort* hp = h2 + (size_t)i * 64;
    float s1 = 0.f, s2 = 0.f;
#pragma unroll
    for (int c = 0; c < 8; ++c) {
        short8 hv = *(const short8*)(hp + c * 8);
#pragma unroll
        for (int j = 0; j < 8; ++j) {
            float v = bf2f((ushort)hv[j]);
            s1 += v * a_src[c * 8 + j];
            s2 += v * a_dst[c * 8 + j];
        }
    }
    asrc[i] = s1;
    adst[i] = s2;
}

// ---------------- fused softmax+aggregation, layers 0/1: one wave per node ----------------
// lanes: hd = lane>>3 (8 lanes per head); passes A/B edge-parallel over lane&7.
__global__ __launch_bounds__(256) void k_agg(const ushort* __restrict__ h,
                                             const float* __restrict__ asrc,
                                             const float* __restrict__ adst,
                                             const int* __restrict__ rowptr,
                                             const int* __restrict__ col,
                                             const float* __restrict__ bias,
                                             ushort* __restrict__ anext, int n) {
    int wid = threadIdx.x >> 6;
    int lane = threadIdx.x & 63;
    int node = blockIdx.x * 4 + wid;
    if (node >= n) return;
    int beg = rowptr[node], end = rowptr[node + 1];
    int hd = lane >> 3;
    int eo = lane & 7;
    float ad = adst[node * 8 + hd];

    // pass A: per-head max (8-lane edge-parallel)
    float m = -1e30f;
    for (int j = beg + eo; j < end; j += 8)
        m = fmaxf(m, lrelu(asrc[col[j] * 8 + hd] + ad));
#pragma unroll
    for (int off = 1; off < 8; off <<= 1) m = fmaxf(m, __shfl_xor(m, off));

    // pass B: per-head exp-sum
    float ssum = 0.f;
    for (int j = beg + eo; j < end; j += 8)
        ssum += __expf(lrelu(asrc[col[j] * 8 + hd] + ad) - m);
#pragma unroll
    for (int off = 1; off < 8; off <<= 1) ssum += __shfl_xor(ssum, off);
    float inv = 1.f / (ssum + 1e-16f);

    // pass C: gather + weighted sum, 4 edges in flight
    float a0 = 0.f, a1 = 0.f, a2 = 0.f, a3 = 0.f;
    int j = beg;
    for (; j + 4 <= end; j += 4) {
        int s0 = col[j], s1 = col[j + 1], s2 = col[j + 2], s3 = col[j + 3];
        us4 g0 = *(const us4*)(h + (size_t)s0 * 256 + lane * 4);
        us4 g1 = *(const us4*)(h + (size_t)s1 * 256 + lane * 4);
        us4 g2 = *(const us4*)(h + (size_t)s2 * 256 + lane * 4);
        us4 g3 = *(const us4*)(h + (size_t)s3 * 256 + lane * 4);
        float w0 = __expf(lrelu(asrc[s0 * 8 + hd] + ad) - m);
        float w1 = __expf(lrelu(asrc[s1 * 8 + hd] + ad) - m);
        float w2 = __expf(lrelu(asrc[s2 * 8 + hd] + ad) - m);
        float w3 = __expf(lrelu(asrc[s3 * 8 + hd] + ad) - m);
        a0 += w0 * bf2f(g0[0]) + w1 * bf2f(g1[0]) + w2 * bf2f(g2[0]) + w3 * bf2f(g3[0]);
        a1 += w0 * bf2f(g0[1]) + w1 * bf2f(g1[1]) + w2 * bf2f(g2[1]) + w3 * bf2f(g3[1]);
        a2 += w0 * bf2f(g0[2]) + w1 * bf2f(g1[2]) + w2 * bf2f(g2[2]) + w3 * bf2f(g3[2]);
        a3 += w0 * bf2f(g0[3]) + w1 * bf2f(g1[3]) + w2 * bf2f(g2[3]) + w3 * bf2f(g3[3]);
    }
    for (; j < end; ++j) {
        int s = col[j];
        us4 g = *(const us4*)(h + (size_t)s * 256 + lane * 4);
        float w = __expf(lrelu(asrc[s * 8 + hd] + ad) - m);
        a0 += w * bf2f(g[0]);
        a1 += w * bf2f(g[1]);
        a2 += w * bf2f(g[2]);
        a3 += w * bf2f(g[3]);
    }
    f32x4 bv = *(const f32x4*)(bias + lane * 4);
    float v0 = a0 * inv + bv[0];
    float v1 = a1 * inv + bv[1];
    float v2 = a2 * inv + bv[2];
    float v3 = a3 * inv + bv[3];
    v0 = (v0 > 0.f) ? v0 : expm1f(v0);
    v1 = (v1 > 0.f) ? v1 : expm1f(v1);
    v2 = (v2 > 0.f) ? v2 : expm1f(v2);
    v3 = (v3 > 0.f) ? v3 : expm1f(v3);
    us4 o;
    o[0] = f2bf(v0); o[1] = f2bf(v1); o[2] = f2bf(v2); o[3] = f2bf(v3);
    *(us4*)(anext + (size_t)node * 256 + lane * 4) = o;
}

// ---------------- fused layer 2 + bias + log_softmax: one wave per node ----------------
__global__ __launch_bounds__(256) void k_agg2(const ushort* __restrict__ h2,
                                              const float* __restrict__ asrc,
                                              const float* __restrict__ adst,
                                              const int* __restrict__ rowptr,
                                              const int* __restrict__ col,
                                              const float* __restrict__ bias,
                                              float* __restrict__ out, int n) {
    int wid = threadIdx.x >> 6;
    int lane = threadIdx.x & 63;
    int node = blockIdx.x * 4 + wid;
    if (node >= n) return;
    int beg = rowptr[node], end = rowptr[node + 1];
    float ad = adst[node];

    float m = -1e30f;
    for (int j = beg + lane; j < end; j += 64)
        m = fmaxf(m, lrelu(asrc[col[j]] + ad));
#pragma unroll
    for (int off = 1; off < 64; off <<= 1) m = fmaxf(m, __shfl_xor(m, off));

    float ssum = 0.f;
    for (int j = beg + lane; j < end; j += 64)
        ssum += __expf(lrelu(asrc[col[j]] + ad) - m);
#pragma unroll
    for (int off = 1; off < 64; off <<= 1) ssum += __shfl_xor(ssum, off);
    float inv = 1.f / (ssum + 1e-16f);

    float acc = 0.f;
    int j = beg;
    for (; j + 4 <= end; j += 4) {
        int s0 = col[j], s1 = col[j + 1], s2 = col[j + 2], s3 = col[j + 3];
        ushort g0 = h2[(size_t)s0 * 64 + lane];
        ushort g1 = h2[(size_t)s1 * 64 + lane];
        ushort g2 = h2[(size_t)s2 * 64 + lane];
        ushort g3 = h2[(size_t)s3 * 64 + lane];
        float w0 = __expf(lrelu(asrc[s0] + ad) - m);
        float w1 = __expf(lrelu(asrc[s1] + ad) - m);
        float w2 = __expf(lrelu(asrc[s2] + ad) - m);
        float w3 = __expf(lrelu(asrc[s3] + ad) - m);
        acc += w0 * bf2f(g0) + w1 * bf2f(g1) + w2 * bf2f(g2) + w3 * bf2f(g3);
    }
    for (; j < end; ++j) {
        int s = col[j];
        float w = __expf(lrelu(asrc[s] + ad) - m);
        acc += w * bf2f(h2[(size_t)s * 64 + lane]);
    }
    float v = acc * inv + bias[lane];
    float mx = v;
#pragma unroll
    for (int off = 32; off > 0; off >>= 1) mx = fmaxf(mx, __shfl_xor(mx, off));
    float ex = __expf(v - mx);
    float se = ex;
#pragma unroll
    for (int off = 32; off > 0; off >>= 1) se += __shfl_xor(se, off);
    out[(size_t)node * 64 + lane] = v - mx - logf(se);
}

extern "C" void kernel_launch(void* const* d_in, const int* in_sizes, int n_in,
                              void* d_out, int out_size, void* d_ws, size_t ws_size,
                              hipStream_t stream) {
    const float* x   = (const float*)d_in[0];
    const int*   ei  = (const int*)d_in[1];
    const float* W0  = (const float*)d_in[2];
    const float* as0 = (const float*)d_in[3];
    const float* ad0 = (const float*)d_in[4];
    const float* b0  = (const float*)d_in[5];
    const float* W1  = (const float*)d_in[6];
    const float* as1 = (const float*)d_in[7];
    const float* ad1 = (const float*)d_in[8];
    const float* b1  = (const float*)d_in[9];
    const float* W2  = (const float*)d_in[10];
    const float* as2 = (const float*)d_in[11];
    const float* ad2 = (const float*)d_in[12];
    const float* b2  = (const float*)d_in[13];
    float* out = (float*)d_out;

    const int N = in_sizes[0] / 512;   // 50000
    const int E = in_sizes[1] / 2;     // 800000
    const int ETOT = E + N;

    char* ws = (char*)d_ws;
    size_t off = 0;
    auto alloc = [&](size_t bytes) -> void* {
        off = (off + 255) & ~(size_t)255;
        void* p = ws + off;
        off += bytes;
        return p;
    };
    int* rowptr = (int*)alloc((size_t)(N + 1) * 4);
    int* cursor = (int*)alloc((size_t)N * 4);
    int* deg    = (int*)alloc((size_t)N * 4);
    int* bsum   = (int*)alloc(1024);
    int* boff   = (int*)alloc(1024);
    int* colb   = (int*)alloc((size_t)ETOT * 4);
    ushort* WT0 = (ushort*)alloc((size_t)256 * 512 * 2);
    ushort* WT1 = (ushort*)alloc((size_t)256 * 256 * 2);
    ushort* WT2 = (ushort*)alloc((size_t)64 * 256 * 2);
    ushort* hbf = (ushort*)alloc((size_t)N * 256 * 2);
    ushort* abf = (ushort*)alloc((size_t)N * 256 * 2);
    float* asrc = (float*)alloc((size_t)N * 8 * 4);
    float* adst = (float*)alloc((size_t)N * 8 * 4);
    // aliases (lifetimes disjoint)
    ushort* h2   = hbf;   // layer-2 gemm output bf16 (6.4MB <= 25.6MB)
    float* asrc2 = asrc;
    float* adst2 = adst;

    const int nblk = (N + 255) / 256;  // 196

    // CSR build
    k_deg_init<<<(N + 255) / 256, 256, 0, stream>>>(deg, N);
    k_hist<<<(E + 255) / 256, 256, 0, stream>>>(ei + E, deg, E);
    k_scanA<<<nblk, 256, 0, stream>>>(deg, bsum, N);
    k_scanB<<<1, 256, 0, stream>>>(bsum, boff, nblk);
    k_scanC<<<nblk, 256, 0, stream>>>(deg, boff, rowptr, cursor, N, ETOT);
    k_scatter<<<(ETOT + 255) / 256, 256, 0, stream>>>(ei, cursor, colb, E, N);

    // weights
    k_wcvt<<<(512 * 256 + 255) / 256, 256, 0, stream>>>(W0, WT0, 512, 256);
    k_wcvt<<<(256 * 256 + 255) / 256, 256, 0, stream>>>(W1, WT1, 256, 256);
    k_wcvt<<<(256 * 64 + 255) / 256, 256, 0, stream>>>(W2, WT2, 256, 64);

    const dim3 g01((N + 127) / 128, 2);  // 391 x 2
    const dim3 g2 ((N + 127) / 128, 1);  // 391 x 1
    const int ablk = (N + 3) / 4;        // 12500

    // layer 0
    k_gemm<512, 128, true, true><<<g01, 256, 0, stream>>>(x, WT0, hbf, N);
    k_alpha<<<(N * 8 + 255) / 256, 256, 0, stream>>>(hbf, as0, ad0, asrc, adst, N);
    k_agg<<<ablk, 256, 0, stream>>>(hbf, asrc, adst, rowptr, colb, b0, abf, N);

    // layer 1
    k_gemm<256, 128, false, true><<<g01, 256, 0, stream>>>(abf, WT1, hbf, N);
    k_alpha<<<(N * 8 + 255) / 256, 256, 0, stream>>>(hbf, as1, ad1, asrc, adst, N);
    k_agg<<<ablk, 256, 0, stream>>>(hbf, asrc, adst, rowptr, colb, b1, abf, N);

    // layer 2
    k_gemm<256, 64, false, true><<<g2, 256, 0, stream>>>(abf, WT2, h2, N);
    k_alpha2<<<(N + 255) / 256, 256, 0, stream>>>(h2, as2, ad2, asrc2, adst2, N);
    k_agg2<<<ablk, 256, 0, stream>>>(h2, asrc2, adst2, rowptr, colb, b2, out, N);
}

// Round 5
// 407.577 us; speedup vs baseline: 2.6418x; 1.0711x over previous
//
#include <hip/hip_runtime.h>
#include <hip/hip_bf16.h>

typedef __attribute__((ext_vector_type(8))) short short8;
typedef __attribute__((ext_vector_type(4))) float f32x4;
typedef __attribute__((ext_vector_type(4))) unsigned short us4;

__device__ __forceinline__ ushort f2bf(float f) {
    unsigned u = __float_as_uint(f);
    u += 0x7FFFu + ((u >> 16) & 1u);
    return (ushort)(u >> 16);
}
__device__ __forceinline__ float bf2f(ushort h) {
    return __uint_as_float(((unsigned)h) << 16);
}
__device__ __forceinline__ float lrelu(float e) { return (e >= 0.f) ? e : 0.2f * e; }
__device__ __forceinline__ void gload16(const void* g, void* l) {
    __builtin_amdgcn_global_load_lds(
        (const __attribute__((address_space(1))) unsigned int*)g,
        (__attribute__((address_space(3))) unsigned int*)l, 16, 0, 0);
}

// ---------------- CSR build ----------------
__global__ void k_deg_init(int* deg, int n) {
    int i = blockIdx.x * blockDim.x + threadIdx.x;
    if (i < n) deg[i] = 1;  // self loop
}
__global__ void k_hist(const int* __restrict__ dst, int* __restrict__ deg, int e) {
    int i = blockIdx.x * blockDim.x + threadIdx.x;
    if (i < e) atomicAdd(&deg[dst[i]], 1);
}
__global__ void k_scanA(const int* __restrict__ deg, int* __restrict__ bsum, int n) {
    __shared__ int sd[256];
    int t = blockIdx.x * 256 + threadIdx.x;
    sd[threadIdx.x] = (t < n) ? deg[t] : 0;
    __syncthreads();
    for (int off = 128; off > 0; off >>= 1) {
        if (threadIdx.x < off) sd[threadIdx.x] += sd[threadIdx.x + off];
        __syncthreads();
    }
    if (threadIdx.x == 0) bsum[blockIdx.x] = sd[0];
}
__global__ void k_scanB(const int* __restrict__ bsum, int* __restrict__ boff, int nb) {
    __shared__ int sd[256];
    int i = threadIdx.x;
    int v = (i < nb) ? bsum[i] : 0;
    sd[i] = v;
    __syncthreads();
    for (int off = 1; off < 256; off <<= 1) {
        int t = (i >= off) ? sd[i - off] : 0;
        __syncthreads();
        sd[i] += t;
        __syncthreads();
    }
    if (i < nb) boff[i] = sd[i] - v;  // exclusive
}
__global__ void k_scanC(const int* __restrict__ deg, const int* __restrict__ boff,
                        int* __restrict__ rowptr, int* __restrict__ cursor, int n, int etot) {
    __shared__ int sd[256];
    int t = blockIdx.x * 256 + threadIdx.x;
    int i = threadIdx.x;
    int v = (t < n) ? deg[t] : 0;
    sd[i] = v;
    __syncthreads();
    for (int off = 1; off < 256; off <<= 1) {
        int tv = (i >= off) ? sd[i - off] : 0;
        __syncthreads();
        sd[i] += tv;
        __syncthreads();
    }
    if (t < n) {
        int ex = boff[blockIdx.x] + sd[i] - v;
        rowptr[t] = ex;
        cursor[t] = ex;
        if (t == n - 1) rowptr[n] = etot;
    }
}
__global__ void k_scatter(const int* __restrict__ ei, int* __restrict__ cursor,
                          int* __restrict__ col, int e, int n) {
    int i = blockIdx.x * blockDim.x + threadIdx.x;
    int etot = e + n;
    if (i >= etot) return;
    int s, d;
    if (i < e) { s = ei[i]; d = ei[e + i]; }
    else       { s = i - e; d = s; }
    int pos = atomicAdd(&cursor[d], 1);
    col[pos] = s;
}

// ---------------- weight transpose + bf16 cvt ----------------
__global__ void k_wcvt(const float* __restrict__ W, ushort* __restrict__ WT, int K, int Nc) {
    int i = blockIdx.x * blockDim.x + threadIdx.x;
    if (i < K * Nc) {
        int k = i / Nc, c = i % Nc;
        WT[(size_t)c * K + k] = f2bf(W[i]);
    }
}

// ---------------- GEMM: C[M,Nc] = A[M,K] x B, B given as BT[Nc][K] bf16 ----------------
template <int K, int BN, bool AF32, bool STORE_BF>
__global__ __launch_bounds__(256) void k_gemm(const void* __restrict__ Ap,
                                              const ushort* __restrict__ BT,
                                              void* __restrict__ Cp, int M) {
    constexpr int BM = 128, BK = 32;
    constexpr int NK = K / BK;
    constexpr int NF = BN / 32;
    constexpr int AU = BM * BK / 8;
    constexpr int BU = BN * BK / 8;
    constexpr int TU = AU + BU;
    __shared__ __align__(16) ushort lds[2][TU * 8];

    const int t = threadIdx.x;
    const int wid = t >> 6, lane = t & 63;
    const int lr = lane & 15, lg = lane >> 4;
    const int wm = wid >> 1, wn = wid & 1;
    const int bm0 = blockIdx.x * BM;
    const int bn0 = blockIdx.y * BN;
    const int Nc = BN * gridDim.y;

    int a_off[4], b_off[NF];
#pragma unroll
    for (int mf = 0; mf < 4; ++mf) {
        int row = wm * 64 + mf * 16 + lr;
        a_off[mf] = row * 64 + ((lg ^ ((row >> 1) & 3)) << 4);
    }
#pragma unroll
    for (int nf = 0; nf < NF; ++nf) {
        int col = wn * (BN / 2) + nf * 16 + lr;
        b_off[nf] = AU * 16 + col * 64 + ((lg ^ ((col >> 1) & 3)) << 4);
    }

    f32x4 acc[4][NF];
#pragma unroll
    for (int mf = 0; mf < 4; ++mf)
#pragma unroll
        for (int nf = 0; nf < NF; ++nf) acc[mf][nf] = f32x4{0.f, 0.f, 0.f, 0.f};

    f32x4 ra[2][2];

    auto stage_B = [&](int buf, int kk) {
#pragma unroll
        for (int i = 0; i < BU / 256; ++i) {
            int u = t + i * 256;
            int col = u >> 2;
            int g = (u & 3) ^ ((col >> 1) & 3);
            const ushort* src = BT + (size_t)(bn0 + col) * K + kk + g * 8;
            gload16(src, &lds[buf][(AU + u) * 8]);
        }
    };
    auto stage_A16 = [&](int buf, int kk) {
#pragma unroll
        for (int i = 0; i < 2; ++i) {
            int u = t + i * 256;
            int row = u >> 2;
            int g = (u & 3) ^ ((row >> 1) & 3);
            int grow = bm0 + row;
            if (grow >= M) grow = M - 1;
            const ushort* src = (const ushort*)Ap + (size_t)grow * K + kk + g * 8;
            gload16(src, &lds[buf][u * 8]);
        }
    };
    auto load_A32 = [&](int kk) {
#pragma unroll
        for (int i = 0; i < 2; ++i) {
            int u = t + i * 256;
            int row = u >> 2;
            int g = (u & 3) ^ ((row >> 1) & 3);
            int grow = bm0 + row;
            if (grow >= M) grow = M - 1;
            const float* src = (const float*)Ap + (size_t)grow * K + kk + g * 8;
            ra[i][0] = *(const f32x4*)src;
            ra[i][1] = *(const f32x4*)(src + 4);
        }
    };
    auto write_A32 = [&](int buf) {
#pragma unroll
        for (int i = 0; i < 2; ++i) {
            int u = t + i * 256;
            short8 v;
#pragma unroll
            for (int j = 0; j < 4; ++j) {
                v[j] = (short)f2bf(ra[i][0][j]);
                v[4 + j] = (short)f2bf(ra[i][1][j]);
            }
            *(short8*)&lds[buf][u * 8] = v;
        }
    };
    auto compute = [&](int buf) {
        const char* base = (const char*)lds[buf];
        short8 af[4], bf_[NF];
#pragma unroll
        for (int mf = 0; mf < 4; ++mf) af[mf] = *(const short8*)(base + a_off[mf]);
#pragma unroll
        for (int nf = 0; nf < NF; ++nf) bf_[nf] = *(const short8*)(base + b_off[nf]);
#pragma unroll
        for (int mf = 0; mf < 4; ++mf)
#pragma unroll
            for (int nf = 0; nf < NF; ++nf)
                acc[mf][nf] = __builtin_amdgcn_mfma_f32_16x16x32_bf16(af[mf], bf_[nf], acc[mf][nf], 0, 0, 0);
    };

    if constexpr (AF32) {
        load_A32(0);
        write_A32(0);
    } else {
        stage_A16(0, 0);
    }
    stage_B(0, 0);
    __syncthreads();

    int buf = 0;
    for (int ks = 0; ks < NK; ++ks) {
        const int kk = (ks + 1) * BK;
        if (ks + 1 < NK) {
            if constexpr (AF32) load_A32(kk);
            else stage_A16(buf ^ 1, kk);
            stage_B(buf ^ 1, kk);
        }
        compute(buf);
        if constexpr (AF32) {
            if (ks + 1 < NK) write_A32(buf ^ 1);
        }
        __syncthreads();
        buf ^= 1;
    }

#pragma unroll
    for (int mf = 0; mf < 4; ++mf) {
#pragma unroll
        for (int nf = 0; nf < NF; ++nf) {
            int col = bn0 + wn * (BN / 2) + nf * 16 + lr;
#pragma unroll
            for (int p = 0; p < 4; ++p) {
                int row = bm0 + wm * 64 + mf * 16 + lg * 4 + p;
                if (row < M) {
                    if (STORE_BF)
                        ((ushort*)Cp)[(size_t)row * Nc + col] = f2bf(acc[mf][nf][p]);
                    else
                        ((float*)Cp)[(size_t)row * Nc + col] = acc[mf][nf][p];
                }
            }
        }
    }
}

// ---------------- attention coefficients ----------------
__global__ void k_alpha(const ushort* __restrict__ h, const float* __restrict__ a_src,
                        const float* __restrict__ a_dst, float* __restrict__ asrc,
                        float* __restrict__ adst, int n) {
    int i = blockIdx.x * blockDim.x + threadIdx.x;
    if (i >= n * 8) return;
    int node = i >> 3, hd = i & 7;
    const ushort* hp = h + (size_t)node * 256 + hd * 32;
    const float* as = a_src + hd * 32;
    const float* ad = a_dst + hd * 32;
    float s1 = 0.f, s2 = 0.f;
#pragma unroll
    for (int c = 0; c < 4; ++c) {
        short8 hv = *(const short8*)(hp + c * 8);
#pragma unroll
        for (int j = 0; j < 8; ++j) {
            float v = bf2f((ushort)hv[j]);
            s1 += v * as[c * 8 + j];
            s2 += v * ad[c * 8 + j];
        }
    }
    asrc[i] = s1;
    adst[i] = s2;
}
__global__ void k_alpha2(const ushort* __restrict__ h2, const float* __restrict__ a_src,
                         const float* __restrict__ a_dst, float* __restrict__ asrc,
                         float* __restrict__ adst, int n) {
    int i = blockIdx.x * blockDim.x + threadIdx.x;
    if (i >= n) return;
    const ushort* hp = h2 + (size_t)i * 64;
    float s1 = 0.f, s2 = 0.f;
#pragma unroll
    for (int c = 0; c < 8; ++c) {
        short8 hv = *(const short8*)(hp + c * 8);
#pragma unroll
        for (int j = 0; j < 8; ++j) {
            float v = bf2f((ushort)hv[j]);
            s1 += v * a_src[c * 8 + j];
            s2 += v * a_dst[c * 8 + j];
        }
    }
    asrc[i] = s1;
    adst[i] = s2;
}

// ---------------- fused softmax+aggregation, layers 0/1: one wave per node ----------------
// No max-subtraction (|e| small for glorot weights + ELU-bounded activations; softmax
// is shift-invariant, exp stays in f32 range). Pass AB computes unnormalized w into
// per-wave LDS + running sum; pass C reads w via ds_read (broadcast).
#define MAXW 96
__global__ __launch_bounds__(256) void k_agg(const ushort* __restrict__ h,
                                             const float* __restrict__ asrc,
                                             const float* __restrict__ adst,
                                             const int* __restrict__ rowptr,
                                             const int* __restrict__ col,
                                             const float* __restrict__ bias,
                                             ushort* __restrict__ anext, int n) {
    __shared__ float wl[4][MAXW * 8];
    int wid = threadIdx.x >> 6;
    int lane = threadIdx.x & 63;
    int node = blockIdx.x * 4 + wid;
    if (node >= n) return;
    int beg = rowptr[node], end = rowptr[node + 1];
    int deg = end - beg;
    int hd = lane >> 3;
    int eo = lane & 7;
    float ad = adst[node * 8 + hd];
    float* wp = wl[wid];

    // pass AB: per-(edge,head) weight + per-head sum, 8-edge-parallel
    float sacc = 0.f;
    for (int jb = eo; jb < deg; jb += 8) {
        int s = col[beg + jb];
        float w = __expf(lrelu(asrc[s * 8 + hd] + ad));
        if (jb < MAXW) wp[jb * 8 + hd] = w;
        sacc += w;
    }
    sacc += __shfl_xor(sacc, 1);
    sacc += __shfl_xor(sacc, 2);
    sacc += __shfl_xor(sacc, 4);
    float inv = 1.f / (sacc + 1e-16f);

    // pass C: gather + weighted sum, 4 edges in flight, w from LDS
    int nl = (deg < MAXW) ? deg : MAXW;
    float a0 = 0.f, a1 = 0.f, a2 = 0.f, a3 = 0.f;
    int jb = 0;
    for (; jb + 4 <= nl; jb += 4) {
        int s0 = col[beg + jb], s1 = col[beg + jb + 1];
        int s2 = col[beg + jb + 2], s3 = col[beg + jb + 3];
        us4 g0 = *(const us4*)(h + (size_t)s0 * 256 + lane * 4);
        us4 g1 = *(const us4*)(h + (size_t)s1 * 256 + lane * 4);
        us4 g2 = *(const us4*)(h + (size_t)s2 * 256 + lane * 4);
        us4 g3 = *(const us4*)(h + (size_t)s3 * 256 + lane * 4);
        float w0 = wp[(jb + 0) * 8 + hd];
        float w1 = wp[(jb + 1) * 8 + hd];
        float w2 = wp[(jb + 2) * 8 + hd];
        float w3 = wp[(jb + 3) * 8 + hd];
        a0 += w0 * bf2f(g0[0]) + w1 * bf2f(g1[0]) + w2 * bf2f(g2[0]) + w3 * bf2f(g3[0]);
        a1 += w0 * bf2f(g0[1]) + w1 * bf2f(g1[1]) + w2 * bf2f(g2[1]) + w3 * bf2f(g3[1]);
        a2 += w0 * bf2f(g0[2]) + w1 * bf2f(g1[2]) + w2 * bf2f(g2[2]) + w3 * bf2f(g3[2]);
        a3 += w0 * bf2f(g0[3]) + w1 * bf2f(g1[3]) + w2 * bf2f(g2[3]) + w3 * bf2f(g3[3]);
    }
    for (; jb < nl; ++jb) {
        int s = col[beg + jb];
        us4 g = *(const us4*)(h + (size_t)s * 256 + lane * 4);
        float w = wp[jb * 8 + hd];
        a0 += w * bf2f(g[0]);
        a1 += w * bf2f(g[1]);
        a2 += w * bf2f(g[2]);
        a3 += w * bf2f(g[3]);
    }
    for (; jb < deg; ++jb) {  // LDS-overflow fallback (deg > MAXW): recompute w
        int s = col[beg + jb];
        us4 g = *(const us4*)(h + (size_t)s * 256 + lane * 4);
        float w = __expf(lrelu(asrc[s * 8 + hd] + ad));
        a0 += w * bf2f(g[0]);
        a1 += w * bf2f(g[1]);
        a2 += w * bf2f(g[2]);
        a3 += w * bf2f(g[3]);
    }
    f32x4 bv = *(const f32x4*)(bias + lane * 4);
    float v0 = a0 * inv + bv[0];
    float v1 = a1 * inv + bv[1];
    float v2 = a2 * inv + bv[2];
    float v3 = a3 * inv + bv[3];
    v0 = (v0 > 0.f) ? v0 : expm1f(v0);
    v1 = (v1 > 0.f) ? v1 : expm1f(v1);
    v2 = (v2 > 0.f) ? v2 : expm1f(v2);
    v3 = (v3 > 0.f) ? v3 : expm1f(v3);
    us4 o;
    o[0] = f2bf(v0); o[1] = f2bf(v1); o[2] = f2bf(v2); o[3] = f2bf(v3);
    *(us4*)(anext + (size_t)node * 256 + lane * 4) = o;
}

// ---------------- fused layer 2 + bias + log_softmax: one wave per node, 1 pass ----------------
__global__ __launch_bounds__(256) void k_agg2(const ushort* __restrict__ h2,
                                              const float* __restrict__ asrc,
                                              const float* __restrict__ adst,
                                              const int* __restrict__ rowptr,
                                              const int* __restrict__ col,
                                              const float* __restrict__ bias,
                                              float* __restrict__ out, int n) {
    int wid = threadIdx.x >> 6;
    int lane = threadIdx.x & 63;
    int node = blockIdx.x * 4 + wid;
    if (node >= n) return;
    int beg = rowptr[node], end = rowptr[node + 1];
    float ad = adst[node];

    float ssum = 0.f, acc = 0.f;
    int j = beg;
    for (; j + 4 <= end; j += 4) {
        int s0 = col[j], s1 = col[j + 1], s2 = col[j + 2], s3 = col[j + 3];
        ushort g0 = h2[(size_t)s0 * 64 + lane];
        ushort g1 = h2[(size_t)s1 * 64 + lane];
        ushort g2 = h2[(size_t)s2 * 64 + lane];
        ushort g3 = h2[(size_t)s3 * 64 + lane];
        float w0 = __expf(lrelu(asrc[s0] + ad));
        float w1 = __expf(lrelu(asrc[s1] + ad));
        float w2 = __expf(lrelu(asrc[s2] + ad));
        float w3 = __expf(lrelu(asrc[s3] + ad));
        ssum += (w0 + w1) + (w2 + w3);
        acc += w0 * bf2f(g0) + w1 * bf2f(g1) + w2 * bf2f(g2) + w3 * bf2f(g3);
    }
    for (; j < end; ++j) {
        int s = col[j];
        float w = __expf(lrelu(asrc[s] + ad));
        ssum += w;
        acc += w * bf2f(h2[(size_t)s * 64 + lane]);
    }
    float v = acc / (ssum + 1e-16f) + bias[lane];
    float mx = v;
#pragma unroll
    for (int off = 32; off > 0; off >>= 1) mx = fmaxf(mx, __shfl_xor(mx, off));
    float ex = __expf(v - mx);
    float se = ex;
#pragma unroll
    for (int off = 32; off > 0; off >>= 1) se += __shfl_xor(se, off);
    out[(size_t)node * 64 + lane] = v - mx - logf(se);
}

extern "C" void kernel_launch(void* const* d_in, const int* in_sizes, int n_in,
                              void* d_out, int out_size, void* d_ws, size_t ws_size,
                              hipStream_t stream) {
    const float* x   = (const float*)d_in[0];
    const int*   ei  = (const int*)d_in[1];
    const float* W0  = (const float*)d_in[2];
    const float* as0 = (const float*)d_in[3];
    const float* ad0 = (const float*)d_in[4];
    const float* b0  = (const float*)d_in[5];
    const float* W1  = (const float*)d_in[6];
    const float* as1 = (const float*)d_in[7];
    const float* ad1 = (const float*)d_in[8];
    const float* b1  = (const float*)d_in[9];
    const float* W2  = (const float*)d_in[10];
    const float* as2 = (const float*)d_in[11];
    const float* ad2 = (const float*)d_in[12];
    const float* b2  = (const float*)d_in[13];
    float* out = (float*)d_out;

    const int N = in_sizes[0] / 512;   // 50000
    const int E = in_sizes[1] / 2;     // 800000
    const int ETOT = E + N;

    char* ws = (char*)d_ws;
    size_t off = 0;
    auto alloc = [&](size_t bytes) -> void* {
        off = (off + 255) & ~(size_t)255;
        void* p = ws + off;
        off += bytes;
        return p;
    };
    int* rowptr = (int*)alloc((size_t)(N + 1) * 4);
    int* cursor = (int*)alloc((size_t)N * 4);
    int* deg    = (int*)alloc((size_t)N * 4);
    int* bsum   = (int*)alloc(1024);
    int* boff   = (int*)alloc(1024);
    int* colb   = (int*)alloc((size_t)ETOT * 4);
    ushort* WT0 = (ushort*)alloc((size_t)256 * 512 * 2);
    ushort* WT1 = (ushort*)alloc((size_t)256 * 256 * 2);
    ushort* WT2 = (ushort*)alloc((size_t)64 * 256 * 2);
    ushort* hbf = (ushort*)alloc((size_t)N * 256 * 2);
    ushort* abf = (ushort*)alloc((size_t)N * 256 * 2);
    float* asrc = (float*)alloc((size_t)N * 8 * 4);
    float* adst = (float*)alloc((size_t)N * 8 * 4);
    // aliases (lifetimes disjoint)
    ushort* h2   = hbf;
    float* asrc2 = asrc;
    float* adst2 = adst;

    const int nblk = (N + 255) / 256;  // 196

    // CSR build
    k_deg_init<<<(N + 255) / 256, 256, 0, stream>>>(deg, N);
    k_hist<<<(E + 255) / 256, 256, 0, stream>>>(ei + E, deg, E);
    k_scanA<<<nblk, 256, 0, stream>>>(deg, bsum, N);
    k_scanB<<<1, 256, 0, stream>>>(bsum, boff, nblk);
    k_scanC<<<nblk, 256, 0, stream>>>(deg, boff, rowptr, cursor, N, ETOT);
    k_scatter<<<(ETOT + 255) / 256, 256, 0, stream>>>(ei, cursor, colb, E, N);

    // weights
    k_wcvt<<<(512 * 256 + 255) / 256, 256, 0, stream>>>(W0, WT0, 512, 256);
    k_wcvt<<<(256 * 256 + 255) / 256, 256, 0, stream>>>(W1, WT1, 256, 256);
    k_wcvt<<<(256 * 64 + 255) / 256, 256, 0, stream>>>(W2, WT2, 256, 64);

    const dim3 g01((N + 127) / 128, 2);  // 391 x 2
    const dim3 g2 ((N + 127) / 128, 1);  // 391 x 1
    const int ablk = (N + 3) / 4;        // 12500

    // layer 0
    k_gemm<512, 128, true, true><<<g01, 256, 0, stream>>>(x, WT0, hbf, N);
    k_alpha<<<(N * 8 + 255) / 256, 256, 0, stream>>>(hbf, as0, ad0, asrc, adst, N);
    k_agg<<<ablk, 256, 0, stream>>>(hbf, asrc, adst, rowptr, colb, b0, abf, N);

    // layer 1
    k_gemm<256, 128, false, true><<<g01, 256, 0, stream>>>(abf, WT1, hbf, N);
    k_alpha<<<(N * 8 + 255) / 256, 256, 0, stream>>>(hbf, as1, ad1, asrc, adst, N);
    k_agg<<<ablk, 256, 0, stream>>>(hbf, asrc, adst, rowptr, colb, b1, abf, N);

    // layer 2
    k_gemm<256, 64, false, true><<<g2, 256, 0, stream>>>(abf, WT2, h2, N);
    k_alpha2<<<(N + 255) / 256, 256, 0, stream>>>(h2, as2, ad2, asrc2, adst2, N);
    k_agg2<<<ablk, 256, 0, stream>>>(h2, asrc2, adst2, rowptr, colb, b2, out, N);
}